// Round 1
// baseline (338.341 us; speedup 1.0000x reference)
//
#include <hip/hip_runtime.h>
#include <math.h>

#define NPTS 4096
#define DD   128
#define NCH  24
#define NHID 5

// ---------------- threefry2x32 (matches JAX's PRNG) ----------------
static __device__ __forceinline__ void tf2x32(unsigned k0, unsigned k1,
                                              unsigned x0, unsigned x1,
                                              unsigned &o0, unsigned &o1) {
  unsigned ks2 = 0x1BD11BDAu ^ k0 ^ k1;
  x0 += k0; x1 += k1;
#define TFR(r) { x0 += x1; x1 = (x1 << (r)) | (x1 >> (32 - (r))); x1 ^= x0; }
  TFR(13) TFR(15) TFR(26) TFR(6)  x0 += k1;  x1 += ks2 + 1u;
  TFR(17) TFR(29) TFR(16) TFR(24) x0 += ks2; x1 += k0 + 2u;
  TFR(13) TFR(15) TFR(26) TFR(6)  x0 += k0;  x1 += k1 + 3u;
  TFR(17) TFR(29) TFR(16) TFR(24) x0 += k1;  x1 += ks2 + 4u;
  TFR(13) TFR(15) TFR(26) TFR(6)  x0 += ks2; x1 += k0 + 5u;
#undef TFR
  o0 = x0; o1 = x1;
}

static __device__ __forceinline__ float bits_to_unif(unsigned b) {
  return __uint_as_float((b >> 9) | 0x3f800000u) - 1.0f;
}

// ---------------- jet composition through a = 0.5*sin(2*pi*h) ----------------
// channels: 0=val, 1..4 = d/d{t,x,y,z},
// 5..13 = {tx,ty,tz,xx,xy,xz,yy,yz,zz},
// 14..22 = d3: {(x,xx),(y,xx),(z,xx),(x,yy),(y,yy),(z,yy),(x,zz),(y,zz),(z,zz)}
// 23 = boundary-path value (independent forward)
static __device__ __forceinline__ void activate_jet(float q[NCH]) {
  const float PI1 = 3.14159265358979323846f;
  const float TWO_PI = 6.283185307179586f;
  float sv, cv;
  sincosf(TWO_PI * q[0], &sv, &cv);
  float p1 = PI1 * cv;
  float p2 = -2.0f * PI1 * PI1 * sv;
  float p3 = -4.0f * PI1 * PI1 * PI1 * cv;
  float g0 = q[1], g1 = q[2], g2 = q[3], g3 = q[4];
  float s_tx = q[5], s_ty = q[6], s_tz = q[7], s_xx = q[8], s_xy = q[9],
        s_xz = q[10], s_yy = q[11], s_yz = q[12], s_zz = q[13];
  float T0 = q[14], T1 = q[15], T2 = q[16], T3 = q[17], T4 = q[18],
        T5 = q[19], T6 = q[20], T7 = q[21], T8 = q[22];

  q[0] = 0.5f * sv;
  q[1] = p1 * g0; q[2] = p1 * g1; q[3] = p1 * g2; q[4] = p1 * g3;
  q[5]  = p2 * g0 * g1 + p1 * s_tx;
  q[6]  = p2 * g0 * g2 + p1 * s_ty;
  q[7]  = p2 * g0 * g3 + p1 * s_tz;
  q[8]  = p2 * g1 * g1 + p1 * s_xx;
  q[9]  = p2 * g1 * g2 + p1 * s_xy;
  q[10] = p2 * g1 * g3 + p1 * s_xz;
  q[11] = p2 * g2 * g2 + p1 * s_yy;
  q[12] = p2 * g2 * g3 + p1 * s_yz;
  q[13] = p2 * g3 * g3 + p1 * s_zz;
  // d3_{i,jj} = p3*g_i*g_j^2 + p2*(2*s_ij*g_j + s_jj*g_i) + p1*t_in
  q[14] = p3 * g1 * g1 * g1 + p2 * (3.0f * s_xx * g1)            + p1 * T0;
  q[15] = p3 * g2 * g1 * g1 + p2 * (2.0f * s_xy * g1 + s_xx * g2) + p1 * T1;
  q[16] = p3 * g3 * g1 * g1 + p2 * (2.0f * s_xz * g1 + s_xx * g3) + p1 * T2;
  q[17] = p3 * g1 * g2 * g2 + p2 * (2.0f * s_xy * g2 + s_yy * g1) + p1 * T3;
  q[18] = p3 * g2 * g2 * g2 + p2 * (3.0f * s_yy * g2)            + p1 * T4;
  q[19] = p3 * g3 * g2 * g2 + p2 * (2.0f * s_yz * g2 + s_yy * g3) + p1 * T5;
  q[20] = p3 * g1 * g3 * g3 + p2 * (2.0f * s_xz * g3 + s_zz * g1) + p1 * T6;
  q[21] = p3 * g2 * g3 * g3 + p2 * (2.0f * s_yz * g3 + s_zz * g2) + p1 * T7;
  q[22] = p3 * g3 * g3 * g3 + p2 * (3.0f * s_zz * g3)            + p1 * T8;
  q[23] = 0.5f * sinf(TWO_PI * q[23]);
}

#define FMA24(A,B,C,E,F,G,wv)                                         \
  acc[0]  = fmaf((A).x, (wv), acc[0]);  acc[1]  = fmaf((A).y, (wv), acc[1]);  \
  acc[2]  = fmaf((A).z, (wv), acc[2]);  acc[3]  = fmaf((A).w, (wv), acc[3]);  \
  acc[4]  = fmaf((B).x, (wv), acc[4]);  acc[5]  = fmaf((B).y, (wv), acc[5]);  \
  acc[6]  = fmaf((B).z, (wv), acc[6]);  acc[7]  = fmaf((B).w, (wv), acc[7]);  \
  acc[8]  = fmaf((C).x, (wv), acc[8]);  acc[9]  = fmaf((C).y, (wv), acc[9]);  \
  acc[10] = fmaf((C).z, (wv), acc[10]); acc[11] = fmaf((C).w, (wv), acc[11]); \
  acc[12] = fmaf((E).x, (wv), acc[12]); acc[13] = fmaf((E).y, (wv), acc[13]); \
  acc[14] = fmaf((E).z, (wv), acc[14]); acc[15] = fmaf((E).w, (wv), acc[15]); \
  acc[16] = fmaf((F).x, (wv), acc[16]); acc[17] = fmaf((F).y, (wv), acc[17]); \
  acc[18] = fmaf((F).z, (wv), acc[18]); acc[19] = fmaf((F).w, (wv), acc[19]); \
  acc[20] = fmaf((G).x, (wv), acc[20]); acc[21] = fmaf((G).y, (wv), acc[21]); \
  acc[22] = fmaf((G).z, (wv), acc[22]); acc[23] = fmaf((G).w, (wv), acc[23]);

__global__ __launch_bounds__(DD) void pinn_kernel(
    const float* __restrict__ inputs, const float* __restrict__ y_true,
    const float* __restrict__ W_in,  const float* __restrict__ b_in,
    const float* __restrict__ W_hid, const float* __restrict__ b_hid,
    const float* __restrict__ W_out, const float* __restrict__ b_out,
    float* __restrict__ out)
{
  __shared__ __align__(16) float hbuf[2][DD][NCH];
  __shared__ float Obuf[4][NCH];

  const int pt = blockIdx.x;
  const int j  = threadIdx.x;

  // ---- boundary randoms: kb1, kb2 = split(key(22)); uniform + randint
  unsigned a0, a1, b0, b1;
  tf2x32(0u, 22u, 0u, 2u, a0, b0);
  tf2x32(0u, 22u, 1u, 3u, a1, b1);
  unsigned f0, f1, zf;
  {
    unsigned jj0 = 2u * (unsigned)pt, jj1 = jj0 + 1u;
    unsigned o0_, o1_;
    if (jj0 < 4096u) { tf2x32(a0, a1, jj0,          jj0 + 4096u, o0_, o1_); f0 = o0_; }
    else             { tf2x32(a0, a1, jj0 - 4096u,  jj0,         o0_, o1_); f0 = o1_; }
    if (jj1 < 4096u) { tf2x32(a0, a1, jj1,          jj1 + 4096u, o0_, o1_); f1 = o0_; }
    else             { tf2x32(a0, a1, jj1 - 4096u,  jj1,         o0_, o1_); f1 = o1_; }
    if (pt < 2048)   { tf2x32(b0, b1, (unsigned)pt,         (unsigned)pt + 2048u, o0_, o1_); zf = o0_; }
    else             { tf2x32(b0, b1, (unsigned)pt - 2048u, (unsigned)pt,         o0_, o1_); zf = o1_; }
  }
  const float xb1f = bits_to_unif(f0);
  const float xb2f = bits_to_unif(f1);
  const unsigned zbit = zf & 1u;
  const float zbf = (float)zbit;
  const float Ttrue = zbit ? -0.5f : 0.5f;

  const float x_t = inputs[pt * 4 + 0];
  const float x_x = inputs[pt * 4 + 1];
  const float x_y = inputs[pt * 4 + 2];
  const float x_z = inputs[pt * 4 + 3];

  // ---- layer 1 (4 -> 128)
  {
    float q[NCH];
    float w0 = W_in[0 * DD + j], w1 = W_in[1 * DD + j],
          w2 = W_in[2 * DD + j], w3 = W_in[3 * DD + j];
    float bb = b_in[j];
    q[0] = bb + x_t * w0 + x_x * w1 + x_y * w2 + x_z * w3;
    q[1] = w0; q[2] = w1; q[3] = w2; q[4] = w3;
#pragma unroll
    for (int c = 5; c < 23; ++c) q[c] = 0.0f;
    q[23] = bb + x_t * w0 + xb1f * w1 + xb2f * w2 + zbf * w3;
    activate_jet(q);
#pragma unroll
    for (int c = 0; c < NCH; ++c) hbuf[0][j][c] = q[c];
  }
  __syncthreads();

  // ---- hidden layers (128 -> 128) x5
  int buf = 0;
  for (int l = 0; l < NHID; ++l) {
    const float* W = W_hid + l * DD * DD + j;
    float acc[NCH];
#pragma unroll
    for (int c = 0; c < NCH; ++c) acc[c] = 0.0f;
    const float* hin = &hbuf[buf][0][0];
#pragma unroll 4
    for (int i = 0; i < DD; ++i) {
      float wv = W[i * DD];
      const float4* hv = (const float4*)(hin + i * NCH);
      float4 A = hv[0], B = hv[1], C = hv[2], E = hv[3], F = hv[4], G = hv[5];
      FMA24(A, B, C, E, F, G, wv)
    }
    float bb = b_hid[l * DD + j];
    acc[0] += bb; acc[23] += bb;
    activate_jet(acc);
#pragma unroll
    for (int c = 0; c < NCH; ++c) hbuf[buf ^ 1][j][c] = acc[c];
    __syncthreads();
    buf ^= 1;
  }

  // ---- output layer (128 -> 4): 32 threads per output, shfl reduce
  {
    const int o = j >> 5;
    const int m = j & 31;
    float acc[NCH];
#pragma unroll
    for (int c = 0; c < NCH; ++c) acc[c] = 0.0f;
    const float* hin = &hbuf[buf][0][0];
#pragma unroll
    for (int ii = 0; ii < 4; ++ii) {
      int i = m + 32 * ii;
      float wv = W_out[i * 4 + o];
      const float4* hv = (const float4*)(hin + i * NCH);
      float4 A = hv[0], B = hv[1], C = hv[2], E = hv[3], F = hv[4], G = hv[5];
      FMA24(A, B, C, E, F, G, wv)
    }
#pragma unroll
    for (int c = 0; c < NCH; ++c) {
      float v = acc[c];
      v += __shfl_xor(v, 1);
      v += __shfl_xor(v, 2);
      v += __shfl_xor(v, 4);
      v += __shfl_xor(v, 8);
      v += __shfl_xor(v, 16);
      acc[c] = v;
    }
    if (m == 0) {
      float bo = b_out[o];
      acc[0] += bo; acc[23] += bo;
#pragma unroll
      for (int c = 0; c < NCH; ++c) Obuf[o][c] = acc[c];
    }
  }
  __syncthreads();

  // ---- epilogue: residuals + loss partial (thread 0)
  if (j == 0) {
    const float S_C = 8.36660026534e-04f;   // sqrt(0.7/1e6)
    const float KAP = 1.19522860933e-03f;   // sqrt(1/(0.7*1e6))
    float (*O)[NCH] = Obuf;

    float u  = O[0][0], v_ = O[1][0], w_ = O[2][0];
    float ux = O[0][2], uy = O[0][3], uz = O[0][4];
    float vx = O[1][2], vy = O[1][3], vz = O[1][4];
    float wx = O[2][2], wy = O[2][3], wz = O[2][4];
    float Tt = O[3][1], Tx = O[3][2], Ty = O[3][3], Tz = O[3][4];

    float NSEu = O[2][6] - O[1][7]
               + u  * (O[2][9]  - O[1][10])
               + v_ * (O[2][11] - O[1][12])
               + w_ * (O[2][12] - O[1][13])
               - (wy - vz) * ux - (uz - wx) * uy - (vx - uy) * uz
               - S_C * (O[2][15] - O[1][16] + O[2][18] - O[1][19] + O[2][21] - O[1][22])
               - Ty;
    float NSEv = O[0][7] - O[2][5]
               + u  * (O[0][10] - O[2][8])
               + v_ * (O[0][12] - O[2][9])
               + w_ * (O[0][13] - O[2][10])
               - (wy - vz) * vx - (uz - wx) * vy - (vx - uy) * vz
               - S_C * (O[0][16] - O[2][14] + O[0][19] - O[2][17] + O[0][22] - O[2][20])
               + Tx;
    float NSEw = O[1][5] - O[0][6]
               + u  * (O[1][8]  - O[0][9])
               + v_ * (O[1][9]  - O[0][11])
               + w_ * (O[1][10] - O[0][12])
               - (wy - vz) * wx - (uz - wx) * wy - (vx - uy) * wz
               - S_C * (O[1][14] - O[0][15] + O[1][17] - O[0][18] + O[1][20] - O[0][21]);

    float EE = Tt + u * Tx + v_ * Ty + w_ * Tz
             - KAP * (O[3][8] + O[3][11] + O[3][13]);

    float conti = ux + vy + wz;

    const float* yt = y_true + pt * 4;
    float d0 = u - yt[0], d1 = v_ - yt[1], d2 = w_ - yt[2];

    float Tb = O[3][23];
    float dT = Ttrue - Tb;

    const float invN  = 1.0f / (float)NPTS;
    const float inv3N = 1.0f / (3.0f * (float)NPTS);
    float part = (d0 * d0 + d1 * d1 + d2 * d2) * inv3N
               + conti * conti * invN
               + (NSEu * NSEu + NSEv * NSEv + NSEw * NSEw) * inv3N
               + EE * EE * invN
               + dT * dT * invN;
    atomicAdd(out, part);
  }
}

extern "C" void kernel_launch(void* const* d_in, const int* in_sizes, int n_in,
                              void* d_out, int out_size, void* d_ws, size_t ws_size,
                              hipStream_t stream) {
  const float* inputs = (const float*)d_in[0];
  const float* y_true = (const float*)d_in[1];
  const float* W_in   = (const float*)d_in[2];
  const float* b_in   = (const float*)d_in[3];
  const float* W_hid  = (const float*)d_in[4];
  const float* b_hid  = (const float*)d_in[5];
  const float* W_out  = (const float*)d_in[6];
  const float* b_out  = (const float*)d_in[7];
  float* out = (float*)d_out;

  hipMemsetAsync(out, 0, sizeof(float), stream);
  pinn_kernel<<<NPTS, DD, 0, stream>>>(inputs, y_true, W_in, b_in,
                                       W_hid, b_hid, W_out, b_out, out);
}

// Round 2
// 182.375 us; speedup vs baseline: 1.8552x; 1.8552x over previous
//
#include <hip/hip_runtime.h>
#include <math.h>

#define NPTS 4096
#define DD   128
#define NCH  24
#define NHID 5
#define PPB  2            // points per block
#define BS   256
#define KSTR 136          // padded k stride (ushorts) for B jet arrays
#define DSTR 50           // Dbuf row stride (floats)

typedef __attribute__((ext_vector_type(8))) short short8;
typedef __attribute__((ext_vector_type(4))) float f32x4;

// ---------------- bf16 split helpers ----------------
static __device__ __forceinline__ unsigned short f2bf(float x) {
  unsigned u = __float_as_uint(x);
  unsigned r = (u + 0x7fffu + ((u >> 16) & 1u)) >> 16;   // RNE
  return (unsigned short)r;
}
static __device__ __forceinline__ float bf2f(unsigned short h) {
  return __uint_as_float(((unsigned)h) << 16);
}

// ---------------- threefry2x32 (matches JAX's PRNG) ----------------
static __device__ __forceinline__ void tf2x32(unsigned k0, unsigned k1,
                                              unsigned x0, unsigned x1,
                                              unsigned &o0, unsigned &o1) {
  unsigned ks2 = 0x1BD11BDAu ^ k0 ^ k1;
  x0 += k0; x1 += k1;
#define TFR(r) { x0 += x1; x1 = (x1 << (r)) | (x1 >> (32 - (r))); x1 ^= x0; }
  TFR(13) TFR(15) TFR(26) TFR(6)  x0 += k1;  x1 += ks2 + 1u;
  TFR(17) TFR(29) TFR(16) TFR(24) x0 += ks2; x1 += k0 + 2u;
  TFR(13) TFR(15) TFR(26) TFR(6)  x0 += k0;  x1 += k1 + 3u;
  TFR(17) TFR(29) TFR(16) TFR(24) x0 += k1;  x1 += ks2 + 4u;
  TFR(13) TFR(15) TFR(26) TFR(6)  x0 += ks2; x1 += k0 + 5u;
#undef TFR
  o0 = x0; o1 = x1;
}
static __device__ __forceinline__ float bits_to_unif(unsigned b) {
  return __uint_as_float((b >> 9) | 0x3f800000u) - 1.0f;
}
// boundary randoms for point pt: xb1, xb2, zbit
static __device__ __forceinline__ void bnd_rand(int pt, float &xb1, float &xb2,
                                                unsigned &zbit) {
  unsigned a0, a1, b0, b1;
  tf2x32(0u, 22u, 0u, 2u, a0, b0);
  tf2x32(0u, 22u, 1u, 3u, a1, b1);
  unsigned f0, f1, zf, o0_, o1_;
  unsigned jj0 = 2u * (unsigned)pt, jj1 = jj0 + 1u;
  if (jj0 < 4096u) { tf2x32(a0, a1, jj0,         jj0 + 4096u, o0_, o1_); f0 = o0_; }
  else             { tf2x32(a0, a1, jj0 - 4096u, jj0,         o0_, o1_); f0 = o1_; }
  if (jj1 < 4096u) { tf2x32(a0, a1, jj1,         jj1 + 4096u, o0_, o1_); f1 = o0_; }
  else             { tf2x32(a0, a1, jj1 - 4096u, jj1,         o0_, o1_); f1 = o1_; }
  if (pt < 2048)   { tf2x32(b0, b1, (unsigned)pt,         (unsigned)pt + 2048u, o0_, o1_); zf = o0_; }
  else             { tf2x32(b0, b1, (unsigned)pt - 2048u, (unsigned)pt,         o0_, o1_); zf = o1_; }
  xb1 = bits_to_unif(f0); xb2 = bits_to_unif(f1); zbit = zf & 1u;
}

// ---------------- jet composition through a = 0.5*sin(2*pi*h) ----------------
// channels: 0=val, 1..4=d/d{t,x,y,z}, 5..13={tx,ty,tz,xx,xy,xz,yy,yz,zz},
// 14..22=d3:{(x,xx),(y,xx),(z,xx),(x,yy),(y,yy),(z,yy),(x,zz),(y,zz),(z,zz)},
// 23 = boundary-path value
static __device__ __forceinline__ void activate_jet(float q[NCH]) {
  const float PI1 = 3.14159265358979323846f;
  const float TWO_PI = 6.283185307179586f;
  float sv, cv;
  sincosf(TWO_PI * q[0], &sv, &cv);
  float p1 = PI1 * cv;
  float p2 = -2.0f * PI1 * PI1 * sv;
  float p3 = -4.0f * PI1 * PI1 * PI1 * cv;
  float g0 = q[1], g1 = q[2], g2 = q[3], g3 = q[4];
  float s_tx = q[5], s_ty = q[6], s_tz = q[7], s_xx = q[8], s_xy = q[9],
        s_xz = q[10], s_yy = q[11], s_yz = q[12], s_zz = q[13];
  float T0 = q[14], T1 = q[15], T2 = q[16], T3 = q[17], T4 = q[18],
        T5 = q[19], T6 = q[20], T7 = q[21], T8 = q[22];
  q[0] = 0.5f * sv;
  q[1] = p1 * g0; q[2] = p1 * g1; q[3] = p1 * g2; q[4] = p1 * g3;
  q[5]  = p2 * g0 * g1 + p1 * s_tx;
  q[6]  = p2 * g0 * g2 + p1 * s_ty;
  q[7]  = p2 * g0 * g3 + p1 * s_tz;
  q[8]  = p2 * g1 * g1 + p1 * s_xx;
  q[9]  = p2 * g1 * g2 + p1 * s_xy;
  q[10] = p2 * g1 * g3 + p1 * s_xz;
  q[11] = p2 * g2 * g2 + p1 * s_yy;
  q[12] = p2 * g2 * g3 + p1 * s_yz;
  q[13] = p2 * g3 * g3 + p1 * s_zz;
  q[14] = p3 * g1 * g1 * g1 + p2 * (3.0f * s_xx * g1)             + p1 * T0;
  q[15] = p3 * g2 * g1 * g1 + p2 * (2.0f * s_xy * g1 + s_xx * g2) + p1 * T1;
  q[16] = p3 * g3 * g1 * g1 + p2 * (2.0f * s_xz * g1 + s_xx * g3) + p1 * T2;
  q[17] = p3 * g1 * g2 * g2 + p2 * (2.0f * s_xy * g2 + s_yy * g1) + p1 * T3;
  q[18] = p3 * g2 * g2 * g2 + p2 * (3.0f * s_yy * g2)             + p1 * T4;
  q[19] = p3 * g3 * g2 * g2 + p2 * (2.0f * s_yz * g2 + s_yy * g3) + p1 * T5;
  q[20] = p3 * g1 * g3 * g3 + p2 * (2.0f * s_xz * g3 + s_zz * g1) + p1 * T6;
  q[21] = p3 * g2 * g3 * g3 + p2 * (2.0f * s_yz * g3 + s_zz * g2) + p1 * T7;
  q[22] = p3 * g3 * g3 * g3 + p2 * (3.0f * s_zz * g3)             + p1 * T8;
  q[23] = 0.5f * sinf(TWO_PI * q[23]);
}

// ---------------- weight prep: W_hid[l][k][m] fp32 -> ws hi/lo [l][m][k] bf16
__global__ __launch_bounds__(256) void prep_weights(
    const float* __restrict__ W_hid, unsigned short* __restrict__ wshi,
    unsigned short* __restrict__ wslo) {
  int idx = blockIdx.x * 256 + threadIdx.x;          // [l][m][k], k fastest
  int l = idx >> 14;
  int rem = idx & 16383;
  int m = rem >> 7, k = rem & 127;
  float w = W_hid[(l << 14) + (k << 7) + m];
  unsigned short hi = f2bf(w);
  unsigned short lo = f2bf(w - bf2f(hi));
  wshi[idx] = hi; wslo[idx] = lo;
}

// ---------------- main kernel ----------------
// LDS layout (51712 B total):
//  [0,13056)        Bhi: ushort[48][136]  (jet hi, B-operand layout: [n][k])
//  [13056,26112)    Blo: ushort[48][136]
//  [26112,51712)    Dbuf: float[128][50]  (GEMM output staging)
//    alias: Wo = Dbuf[0..512) floats; Obuf = floats at +2048 B (2*4*24)
__global__ __launch_bounds__(BS) void pinn_kernel(
    const float* __restrict__ inputs, const float* __restrict__ y_true,
    const float* __restrict__ W_in,  const float* __restrict__ b_in,
    const float* __restrict__ b_hid,
    const float* __restrict__ W_out, const float* __restrict__ b_out,
    const unsigned short* __restrict__ wshi,
    const unsigned short* __restrict__ wslo,
    float* __restrict__ out)
{
  __shared__ __align__(16) unsigned char smem[51712];
  unsigned short* Bhi = (unsigned short*)smem;
  unsigned short* Blo = (unsigned short*)(smem + 13056);
  float* Dbuf = (float*)(smem + 26112);
  float* Wo   = (float*)(smem + 26112);           // alias (used post-GEMM)
  float* Obuf = (float*)(smem + 26112 + 2048);    // alias

  const int t    = threadIdx.x;
  const int wave = t >> 6;
  const int lane = t & 63;
  const int quad = lane >> 4;
  const int nl   = lane & 15;
  const int pt0  = blockIdx.x * PPB;

  // ---- layer 1 (4 -> 128), scalar fp32, thread -> (p, j)
  {
    const int p = t >> 7, j = t & 127;
    const int pt = pt0 + p;
    float xb1, xb2; unsigned zbit;
    bnd_rand(pt, xb1, xb2, zbit);
    float x_t = inputs[pt * 4 + 0], x_x = inputs[pt * 4 + 1];
    float x_y = inputs[pt * 4 + 2], x_z = inputs[pt * 4 + 3];
    float w0 = W_in[0 * DD + j], w1 = W_in[1 * DD + j],
          w2 = W_in[2 * DD + j], w3 = W_in[3 * DD + j];
    float bb = b_in[j];
    float q[NCH];
    q[0] = bb + x_t * w0 + x_x * w1 + x_y * w2 + x_z * w3;
    q[1] = w0; q[2] = w1; q[3] = w2; q[4] = w3;
#pragma unroll
    for (int c = 5; c < 23; ++c) q[c] = 0.0f;
    q[23] = bb + x_t * w0 + xb1 * w1 + xb2 * w2 + (float)zbit * w3;
    activate_jet(q);
#pragma unroll
    for (int c = 0; c < NCH; ++c) {
      int n = p * NCH + c;
      unsigned short hi = f2bf(q[c]);
      unsigned short lo = f2bf(q[c] - bf2f(hi));
      Bhi[n * KSTR + j] = hi;
      Blo[n * KSTR + j] = lo;
    }
  }

  // ---- hidden layers: GEMM M=128 x N=48 x K=128, split-bf16 3-MFMA
  for (int l = 0; l < NHID; ++l) {
    __syncthreads();   // (A) jets in Bhi/Blo ready; Dbuf free
    f32x4 acc[2][3];
#pragma unroll
    for (int mt = 0; mt < 2; ++mt)
#pragma unroll
      for (int nt = 0; nt < 3; ++nt) acc[mt][nt] = (f32x4)0.0f;

    const short8* pBhi = (const short8*)Bhi;
    const short8* pBlo = (const short8*)Blo;
    const short8* pAhi = ((const short8*)wshi) + (l << 11);
    const short8* pAlo = ((const short8*)wslo) + (l << 11);

#pragma unroll
    for (int ks = 0; ks < 4; ++ks) {
      short8 bh[3], bl[3], ah[2], al[2];
#pragma unroll
      for (int nt = 0; nt < 3; ++nt) {
        int bidx = (nt * 16 + nl) * 17 + ks * 4 + quad;   // KSTR/8 = 17
        bh[nt] = pBhi[bidx];
        bl[nt] = pBlo[bidx];
      }
#pragma unroll
      for (int mt = 0; mt < 2; ++mt) {
        int m = (wave << 5) + (mt << 4) + nl;
        int aidx = m * 16 + ks * 4 + quad;
        ah[mt] = pAhi[aidx];
        al[mt] = pAlo[aidx];
      }
#pragma unroll
      for (int mt = 0; mt < 2; ++mt)
#pragma unroll
        for (int nt = 0; nt < 3; ++nt) {
          acc[mt][nt] = __builtin_amdgcn_mfma_f32_16x16x32_bf16(ah[mt], bh[nt], acc[mt][nt], 0, 0, 0);
          acc[mt][nt] = __builtin_amdgcn_mfma_f32_16x16x32_bf16(ah[mt], bl[nt], acc[mt][nt], 0, 0, 0);
          acc[mt][nt] = __builtin_amdgcn_mfma_f32_16x16x32_bf16(al[mt], bh[nt], acc[mt][nt], 0, 0, 0);
        }
    }
    // store D: col n = nt*16+nl, row m = wave*32 + mt*16 + quad*4 + r
#pragma unroll
    for (int mt = 0; mt < 2; ++mt)
#pragma unroll
      for (int nt = 0; nt < 3; ++nt) {
        int n = nt * 16 + nl;
        int mb = (wave << 5) + (mt << 4) + (quad << 2);
#pragma unroll
        for (int r = 0; r < 4; ++r)
          Dbuf[(mb + r) * DSTR + n] = acc[mt][nt][r];
      }
    __syncthreads();   // (B) D complete; B arrays free to overwrite

    // activation epilogue: thread -> (p, j)
    {
      const int p = t >> 7, j = t & 127;
      const float* bp = Dbuf + j * DSTR + p * NCH;
      float q[NCH];
#pragma unroll
      for (int u = 0; u < 12; ++u) {
        float2 tmp = *(const float2*)(bp + 2 * u);
        q[2 * u] = tmp.x; q[2 * u + 1] = tmp.y;
      }
      float bb = b_hid[l * DD + j];
      q[0] += bb; q[23] += bb;
      activate_jet(q);
#pragma unroll
      for (int c = 0; c < NCH; ++c) {
        int n = p * NCH + c;
        unsigned short hi = f2bf(q[c]);
        unsigned short lo = f2bf(q[c] - bf2f(hi));
        Bhi[n * KSTR + j] = hi;
        Blo[n * KSTR + j] = lo;
      }
    }
  }
  __syncthreads();   // final jets ready; Dbuf free

  // stage W_out^T into LDS: Wo[o][jv] = W_out[jv*4+o]
  for (int idx = t; idx < 512; idx += BS) {
    int o = idx & 3, jv = idx >> 2;
    Wo[o * 128 + jv] = W_out[idx];
  }
  __syncthreads();

  // ---- output layer: thread -> (p, o, c), sum over 128 hidden neurons
  if (t < PPB * 4 * NCH) {
    int p = t / 96, r = t % 96, o = r / 24, c = r % 24;
    int n = p * NCH + c;
    const short8* ph = (const short8*)Bhi;
    const short8* pl = (const short8*)Blo;
    float s = 0.0f;
#pragma unroll
    for (int jj = 0; jj < 16; ++jj) {
      short8 h8 = ph[n * 17 + jj];
      short8 l8 = pl[n * 17 + jj];
#pragma unroll
      for (int r2 = 0; r2 < 8; ++r2) {
        float hv = bf2f((unsigned short)h8[r2]) + bf2f((unsigned short)l8[r2]);
        s = fmaf(hv, Wo[o * 128 + jj * 8 + r2], s);
      }
    }
    if (c == 0 || c == 23) s += b_out[o];
    Obuf[(p * 4 + o) * NCH + c] = s;
  }
  __syncthreads();

  // ---- loss epilogue: thread p in {0,1}
  if (t < PPB) {
    const int p = t;
    const int pt = pt0 + p;
    float xb1_, xb2_; unsigned zbit;
    bnd_rand(pt, xb1_, xb2_, zbit);
    const float Ttrue = zbit ? -0.5f : 0.5f;
    const float S_C = 8.36660026534e-04f;   // sqrt(0.7/1e6)
    const float KAP = 1.19522860933e-03f;   // sqrt(1/(0.7*1e6))
#define OO(o, c) Obuf[((p << 2) + (o)) * NCH + (c)]
    float u  = OO(0, 0), v_ = OO(1, 0), w_ = OO(2, 0);
    float ux = OO(0, 2), uy = OO(0, 3), uz = OO(0, 4);
    float vx = OO(1, 2), vy = OO(1, 3), vz = OO(1, 4);
    float wx = OO(2, 2), wy = OO(2, 3), wz = OO(2, 4);
    float Tt = OO(3, 1), Tx = OO(3, 2), Ty = OO(3, 3), Tz = OO(3, 4);

    float NSEu = OO(2, 6) - OO(1, 7)
               + u  * (OO(2, 9)  - OO(1, 10))
               + v_ * (OO(2, 11) - OO(1, 12))
               + w_ * (OO(2, 12) - OO(1, 13))
               - (wy - vz) * ux - (uz - wx) * uy - (vx - uy) * uz
               - S_C * (OO(2, 15) - OO(1, 16) + OO(2, 18) - OO(1, 19) + OO(2, 21) - OO(1, 22))
               - Ty;
    float NSEv = OO(0, 7) - OO(2, 5)
               + u  * (OO(0, 10) - OO(2, 8))
               + v_ * (OO(0, 12) - OO(2, 9))
               + w_ * (OO(0, 13) - OO(2, 10))
               - (wy - vz) * vx - (uz - wx) * vy - (vx - uy) * vz
               - S_C * (OO(0, 16) - OO(2, 14) + OO(0, 19) - OO(2, 17) + OO(0, 22) - OO(2, 20))
               + Tx;
    float NSEw = OO(1, 5) - OO(0, 6)
               + u  * (OO(1, 8)  - OO(0, 9))
               + v_ * (OO(1, 9)  - OO(0, 11))
               + w_ * (OO(1, 10) - OO(0, 12))
               - (wy - vz) * wx - (uz - wx) * wy - (vx - uy) * wz
               - S_C * (OO(1, 14) - OO(0, 15) + OO(1, 17) - OO(0, 18) + OO(1, 20) - OO(0, 21));

    float EE = Tt + u * Tx + v_ * Ty + w_ * Tz
             - KAP * (OO(3, 8) + OO(3, 11) + OO(3, 13));

    float conti = ux + vy + wz;
    const float* yt = y_true + pt * 4;
    float d0 = u - yt[0], d1 = v_ - yt[1], d2 = w_ - yt[2];
    float dT = Ttrue - OO(3, 23);
#undef OO
    const float invN  = 1.0f / (float)NPTS;
    const float inv3N = 1.0f / (3.0f * (float)NPTS);
    float part = (d0 * d0 + d1 * d1 + d2 * d2) * inv3N
               + conti * conti * invN
               + (NSEu * NSEu + NSEv * NSEv + NSEw * NSEw) * inv3N
               + EE * EE * invN
               + dT * dT * invN;
    atomicAdd(out, part);
  }
}

extern "C" void kernel_launch(void* const* d_in, const int* in_sizes, int n_in,
                              void* d_out, int out_size, void* d_ws, size_t ws_size,
                              hipStream_t stream) {
  const float* inputs = (const float*)d_in[0];
  const float* y_true = (const float*)d_in[1];
  const float* W_in   = (const float*)d_in[2];
  const float* b_in   = (const float*)d_in[3];
  const float* W_hid  = (const float*)d_in[4];
  const float* b_hid  = (const float*)d_in[5];
  const float* W_out  = (const float*)d_in[6];
  const float* b_out  = (const float*)d_in[7];
  float* out = (float*)d_out;

  unsigned short* wshi = (unsigned short*)d_ws;            // 5*128*128 ushort
  unsigned short* wslo = wshi + NHID * DD * DD;            // +163840 B

  hipMemsetAsync(out, 0, sizeof(float), stream);
  prep_weights<<<(NHID * DD * DD) / 256, 256, 0, stream>>>(W_hid, wshi, wslo);
  pinn_kernel<<<NPTS / PPB, BS, 0, stream>>>(inputs, y_true, W_in, b_in,
                                             b_hid, W_out, b_out,
                                             wshi, wslo, out);
}

// Round 4
// 179.993 us; speedup vs baseline: 1.8797x; 1.0132x over previous
//
#include <hip/hip_runtime.h>
#include <math.h>

#define NPTS 4096
#define DD   128
#define NCH  24
#define NHID 5
#define PPB  2            // points per block
#define BS   256
#define KSTR 136          // padded k stride (ushorts) for B jet arrays
#define DST  132          // D row stride (floats), layout D[n][m]

typedef __attribute__((ext_vector_type(8))) short short8;
typedef __attribute__((ext_vector_type(4))) float f32x4;

// ---------------- bf16 helpers ----------------
static __device__ __forceinline__ unsigned short f2bf(float x) {
  unsigned u = __float_as_uint(x);
  unsigned r = (u + 0x7fffu + ((u >> 16) & 1u)) >> 16;   // RNE
  return (unsigned short)r;
}
static __device__ __forceinline__ float bf2f(unsigned short h) {
  return __uint_as_float(((unsigned)h) << 16);
}
// truncation split: x ~= hi + lo to ~2^-16 rel; ~4 VALU inst
static __device__ __forceinline__ void split_tr(float x, unsigned short &hi,
                                                unsigned short &lo) {
  unsigned u = __float_as_uint(x);
  hi = (unsigned short)(u >> 16);
  float rem = x - __uint_as_float(u & 0xffff0000u);
  lo = (unsigned short)(__float_as_uint(rem) >> 16);
}

// ---------------- threefry2x32 (matches JAX's PRNG) ----------------
static __device__ __forceinline__ void tf2x32(unsigned k0, unsigned k1,
                                              unsigned x0, unsigned x1,
                                              unsigned &o0, unsigned &o1) {
  unsigned ks2 = 0x1BD11BDAu ^ k0 ^ k1;
  x0 += k0; x1 += k1;
#define TFR(r) { x0 += x1; x1 = (x1 << (r)) | (x1 >> (32 - (r))); x1 ^= x0; }
  TFR(13) TFR(15) TFR(26) TFR(6)  x0 += k1;  x1 += ks2 + 1u;
  TFR(17) TFR(29) TFR(16) TFR(24) x0 += ks2; x1 += k0 + 2u;
  TFR(13) TFR(15) TFR(26) TFR(6)  x0 += k0;  x1 += k1 + 3u;
  TFR(17) TFR(29) TFR(16) TFR(24) x0 += k1;  x1 += ks2 + 4u;
  TFR(13) TFR(15) TFR(26) TFR(6)  x0 += ks2; x1 += k0 + 5u;
#undef TFR
  o0 = x0; o1 = x1;
}
static __device__ __forceinline__ float bits_to_unif(unsigned b) {
  return __uint_as_float((b >> 9) | 0x3f800000u) - 1.0f;
}
static __device__ __forceinline__ void bnd_rand(int pt, float &xb1, float &xb2,
                                                unsigned &zbit) {
  unsigned a0, a1, b0, b1;
  tf2x32(0u, 22u, 0u, 2u, a0, b0);
  tf2x32(0u, 22u, 1u, 3u, a1, b1);
  unsigned f0, f1, zf, o0_, o1_;
  unsigned jj0 = 2u * (unsigned)pt, jj1 = jj0 + 1u;
  if (jj0 < 4096u) { tf2x32(a0, a1, jj0,         jj0 + 4096u, o0_, o1_); f0 = o0_; }
  else             { tf2x32(a0, a1, jj0 - 4096u, jj0,         o0_, o1_); f0 = o1_; }
  if (jj1 < 4096u) { tf2x32(a0, a1, jj1,         jj1 + 4096u, o0_, o1_); f1 = o0_; }
  else             { tf2x32(a0, a1, jj1 - 4096u, jj1,         o0_, o1_); f1 = o1_; }
  if (pt < 2048)   { tf2x32(b0, b1, (unsigned)pt,         (unsigned)pt + 2048u, o0_, o1_); zf = o0_; }
  else             { tf2x32(b0, b1, (unsigned)pt - 2048u, (unsigned)pt,         o0_, o1_); zf = o1_; }
  xb1 = bits_to_unif(f0); xb2 = bits_to_unif(f1); zbit = zf & 1u;
}

// ---------------- jet composition through a = 0.5*sin(2*pi*h) ----------------
// channels: 0=val, 1..4=d/d{t,x,y,z}, 5..13={tx,ty,tz,xx,xy,xz,yy,yz,zz},
// 14..22=d3:{(x,xx),(y,xx),(z,xx),(x,yy),(y,yy),(z,yy),(x,zz),(y,zz),(z,zz)},
// 23 = boundary-path value
static __device__ __forceinline__ void activate_jet(float q[NCH]) {
  const float PI1 = 3.14159265358979323846f;
  // v_sin/v_cos take revolutions: sin(2*pi*h) = v_sin(fract(h))
  float hr = q[0] - floorf(q[0]);
  float sv = __builtin_amdgcn_sinf(hr);
  float cv = __builtin_amdgcn_cosf(hr);
  float p1 = PI1 * cv;
  float p2 = -2.0f * PI1 * PI1 * sv;
  float p3 = -4.0f * PI1 * PI1 * PI1 * cv;
  float g0 = q[1], g1 = q[2], g2 = q[3], g3 = q[4];
  float s_tx = q[5], s_ty = q[6], s_tz = q[7], s_xx = q[8], s_xy = q[9],
        s_xz = q[10], s_yy = q[11], s_yz = q[12], s_zz = q[13];
  float T0 = q[14], T1 = q[15], T2 = q[16], T3 = q[17], T4 = q[18],
        T5 = q[19], T6 = q[20], T7 = q[21], T8 = q[22];
  q[0] = 0.5f * sv;
  q[1] = p1 * g0; q[2] = p1 * g1; q[3] = p1 * g2; q[4] = p1 * g3;
  q[5]  = p2 * g0 * g1 + p1 * s_tx;
  q[6]  = p2 * g0 * g2 + p1 * s_ty;
  q[7]  = p2 * g0 * g3 + p1 * s_tz;
  q[8]  = p2 * g1 * g1 + p1 * s_xx;
  q[9]  = p2 * g1 * g2 + p1 * s_xy;
  q[10] = p2 * g1 * g3 + p1 * s_xz;
  q[11] = p2 * g2 * g2 + p1 * s_yy;
  q[12] = p2 * g2 * g3 + p1 * s_yz;
  q[13] = p2 * g3 * g3 + p1 * s_zz;
  q[14] = p3 * g1 * g1 * g1 + p2 * (3.0f * s_xx * g1)             + p1 * T0;
  q[15] = p3 * g2 * g1 * g1 + p2 * (2.0f * s_xy * g1 + s_xx * g2) + p1 * T1;
  q[16] = p3 * g3 * g1 * g1 + p2 * (2.0f * s_xz * g1 + s_xx * g3) + p1 * T2;
  q[17] = p3 * g1 * g2 * g2 + p2 * (2.0f * s_xy * g2 + s_yy * g1) + p1 * T3;
  q[18] = p3 * g2 * g2 * g2 + p2 * (3.0f * s_yy * g2)             + p1 * T4;
  q[19] = p3 * g3 * g2 * g2 + p2 * (2.0f * s_yz * g2 + s_yy * g3) + p1 * T5;
  q[20] = p3 * g1 * g3 * g3 + p2 * (2.0f * s_xz * g3 + s_zz * g1) + p1 * T6;
  q[21] = p3 * g2 * g3 * g3 + p2 * (2.0f * s_yz * g3 + s_zz * g2) + p1 * T7;
  q[22] = p3 * g3 * g3 * g3 + p2 * (3.0f * s_zz * g3)             + p1 * T8;
  float br = q[23] - floorf(q[23]);
  q[23] = 0.5f * __builtin_amdgcn_sinf(br);
}

// ---------------- prep: weight split + W_out^T pad/split + boundary RNG ----
__global__ __launch_bounds__(256) void prep_kernel(
    const float* __restrict__ W_hid, const float* __restrict__ W_out,
    unsigned short* __restrict__ wshi, unsigned short* __restrict__ wslo,
    unsigned short* __restrict__ aohi, unsigned short* __restrict__ aolo,
    float4* __restrict__ rnd) {
  int b = blockIdx.x;
  if (b < 320) {
    int idx = b * 256 + threadIdx.x;          // [l][m][k], k fastest
    int l = idx >> 14, rem = idx & 16383, m = rem >> 7, k = rem & 127;
    float w = W_hid[(l << 14) + (k << 7) + m];
    unsigned short hi = f2bf(w);
    wshi[idx] = hi; wslo[idx] = f2bf(w - bf2f(hi));
  } else if (b < 328) {
    int idx = (b - 320) * 256 + threadIdx.x;  // [m=16][k=128]
    int m = idx >> 7, k = idx & 127;
    float w = (m < 4) ? W_out[k * 4 + m] : 0.0f;
    unsigned short hi = f2bf(w);
    aohi[idx] = hi; aolo[idx] = f2bf(w - bf2f(hi));
  } else {
    int pt = (b - 328) * 256 + threadIdx.x;   // 4096 points
    float xb1, xb2; unsigned zbit;
    bnd_rand(pt, xb1, xb2, zbit);
    rnd[pt] = make_float4(xb1, xb2, (float)zbit, zbit ? -0.5f : 0.5f);
  }
}

// ---------------- main kernel ----------------
// LDS (26176 B): B region [0,26112) = Bhi[48][136] + Blo[48][136] (ushort)
// D aliases the same region: float D[48][DST=132]  (25344 B)
// Hazards handled by 4 barriers/layer (see flow comments).
__global__ __launch_bounds__(BS, 6) void pinn_kernel(
    const float* __restrict__ inputs, const float* __restrict__ y_true,
    const float* __restrict__ W_in,  const float* __restrict__ b_in,
    const float* __restrict__ b_hid, const float* __restrict__ b_out,
    const unsigned short* __restrict__ wshi,
    const unsigned short* __restrict__ wslo,
    const unsigned short* __restrict__ aohi,
    const unsigned short* __restrict__ aolo,
    const float4* __restrict__ rnd,
    float* __restrict__ out)
{
  __shared__ __align__(16) unsigned char smem[26176];
  unsigned short* Bhi = (unsigned short*)smem;
  unsigned short* Blo = (unsigned short*)(smem + 13056);
  float* D = (float*)smem;                     // ALIAS of B region

  const int t    = threadIdx.x;
  const int wave = t >> 6;
  const int lane = t & 63;
  const int quad = lane >> 4;
  const int nl   = lane & 15;
  const int pt0  = blockIdx.x * PPB;
  const int p    = t >> 7;       // point within block (epilogue mapping)
  const int j    = t & 127;      // neuron (epilogue mapping)
  const int pt   = pt0 + p;

  // ---- layer 1 (4 -> 128), scalar fp32
  {
    float4 rv = rnd[pt];
    float x_t = inputs[pt * 4 + 0], x_x = inputs[pt * 4 + 1];
    float x_y = inputs[pt * 4 + 2], x_z = inputs[pt * 4 + 3];
    float w0 = W_in[0 * DD + j], w1 = W_in[1 * DD + j],
          w2 = W_in[2 * DD + j], w3 = W_in[3 * DD + j];
    float bb = b_in[j];
    float q[NCH];
    q[0] = bb + x_t * w0 + x_x * w1 + x_y * w2 + x_z * w3;
    q[1] = w0; q[2] = w1; q[3] = w2; q[4] = w3;
#pragma unroll
    for (int c = 5; c < 23; ++c) q[c] = 0.0f;
    q[23] = bb + x_t * w0 + rv.x * w1 + rv.y * w2 + rv.z * w3;
    activate_jet(q);
#pragma unroll
    for (int c = 0; c < NCH; ++c) {
      int n = p * NCH + c;
      unsigned short hi, lo;
      split_tr(q[c], hi, lo);
      Bhi[n * KSTR + j] = hi;
      Blo[n * KSTR + j] = lo;
    }
  }

  // ---- hidden layers: GEMM M=128 x N=48 x K=128, split-bf16 3-MFMA
  for (int l = 0; l < NHID; ++l) {
    __syncthreads();   // (1) B writes visible
    f32x4 acc[2][3];
#pragma unroll
    for (int mt = 0; mt < 2; ++mt)
#pragma unroll
      for (int nt = 0; nt < 3; ++nt) acc[mt][nt] = (f32x4)0.0f;

    const short8* pBhi = (const short8*)Bhi;
    const short8* pBlo = (const short8*)Blo;
    const short8* pAhi = ((const short8*)wshi) + (l << 11);
    const short8* pAlo = ((const short8*)wslo) + (l << 11);

#pragma unroll
    for (int ks = 0; ks < 4; ++ks) {
      short8 bh[3], bl[3], ah[2], al[2];
#pragma unroll
      for (int nt = 0; nt < 3; ++nt) {
        int bidx = (nt * 16 + nl) * 17 + ks * 4 + quad;   // KSTR/8 = 17
        bh[nt] = pBhi[bidx];
        bl[nt] = pBlo[bidx];
      }
#pragma unroll
      for (int mt = 0; mt < 2; ++mt) {
        int m = (wave << 5) + (mt << 4) + nl;
        int aidx = m * 16 + ks * 4 + quad;
        ah[mt] = pAhi[aidx];
        al[mt] = pAlo[aidx];
      }
#pragma unroll
      for (int mt = 0; mt < 2; ++mt)
#pragma unroll
        for (int nt = 0; nt < 3; ++nt) {
          acc[mt][nt] = __builtin_amdgcn_mfma_f32_16x16x32_bf16(ah[mt], bh[nt], acc[mt][nt], 0, 0, 0);
          acc[mt][nt] = __builtin_amdgcn_mfma_f32_16x16x32_bf16(ah[mt], bl[nt], acc[mt][nt], 0, 0, 0);
          acc[mt][nt] = __builtin_amdgcn_mfma_f32_16x16x32_bf16(al[mt], bh[nt], acc[mt][nt], 0, 0, 0);
        }
    }
    __syncthreads();   // (2) all B reads done; safe to overwrite with D

    // store D[n][m]: col n = nt*16+nl, rows m = wave*32+mt*16+quad*4 .. +3
#pragma unroll
    for (int mt = 0; mt < 2; ++mt)
#pragma unroll
      for (int nt = 0; nt < 3; ++nt) {
        int n  = nt * 16 + nl;
        int mb = (wave << 5) + (mt << 4) + (quad << 2);
        *(f32x4*)(D + n * DST + mb) = acc[mt][nt];
      }
    __syncthreads();   // (3) D complete

    // epilogue: thread (p,j) reads its 24 channels (stride-DST, conflict-free)
    float q[NCH];
#pragma unroll
    for (int c = 0; c < NCH; ++c) q[c] = D[(p * NCH + c) * DST + j];
    __syncthreads();   // (4) all D reads done; safe to overwrite with B

    float bb = b_hid[l * DD + j];
    q[0] += bb; q[23] += bb;
    activate_jet(q);
#pragma unroll
    for (int c = 0; c < NCH; ++c) {
      int n = p * NCH + c;
      unsigned short hi, lo;
      split_tr(q[c], hi, lo);
      Bhi[n * KSTR + j] = hi;
      Blo[n * KSTR + j] = lo;
    }
  }
  __syncthreads();     // final jets ready

  // ---- output layer as padded M=16 GEMM (wave 0 only).
  // Stores D over B region: wave-local read-before-write is guaranteed by
  // data deps (all MFMAs consume B reads before acc is final).
  if (wave == 0) {
    f32x4 acc2[3];
#pragma unroll
    for (int nt = 0; nt < 3; ++nt) acc2[nt] = (f32x4)0.0f;
    const short8* pBhi = (const short8*)Bhi;
    const short8* pBlo = (const short8*)Blo;
    const short8* pAh  = (const short8*)aohi;
    const short8* pAl  = (const short8*)aolo;
#pragma unroll
    for (int ks = 0; ks < 4; ++ks) {
      short8 bh[3], bl[3];
#pragma unroll
      for (int nt = 0; nt < 3; ++nt) {
        int bidx = (nt * 16 + nl) * 17 + ks * 4 + quad;
        bh[nt] = pBhi[bidx];
        bl[nt] = pBlo[bidx];
      }
      short8 ah = pAh[nl * 16 + ks * 4 + quad];
      short8 al = pAl[nl * 16 + ks * 4 + quad];
#pragma unroll
      for (int nt = 0; nt < 3; ++nt) {
        acc2[nt] = __builtin_amdgcn_mfma_f32_16x16x32_bf16(ah, bh[nt], acc2[nt], 0, 0, 0);
        acc2[nt] = __builtin_amdgcn_mfma_f32_16x16x32_bf16(ah, bl[nt], acc2[nt], 0, 0, 0);
        acc2[nt] = __builtin_amdgcn_mfma_f32_16x16x32_bf16(al, bh[nt], acc2[nt], 0, 0, 0);
      }
    }
#pragma unroll
    for (int nt = 0; nt < 3; ++nt) {
      int n = nt * 16 + nl;
      *(f32x4*)(D + n * DST + (quad << 2)) = acc2[nt];
    }
  }
  __syncthreads();     // O (in D) ready

  // ---- loss epilogue: threads 0,1 (p = t)
  if (t < PPB) {
    const int pp = t;
    const int ptt = pt0 + pp;
    const float Ttrue = rnd[ptt].w;
    const float S_C = 8.36660026534e-04f;   // sqrt(0.7/1e6)
    const float KAP = 1.19522860933e-03f;   // sqrt(1/(0.7*1e6))
    float bo0 = b_out[0], bo1 = b_out[1], bo2 = b_out[2], bo3 = b_out[3];
#define OO(o, c) D[((pp) * NCH + (c)) * DST + (o)]
    float u  = OO(0, 0) + bo0, v_ = OO(1, 0) + bo1, w_ = OO(2, 0) + bo2;
    float ux = OO(0, 2), uy = OO(0, 3), uz = OO(0, 4);
    float vx = OO(1, 2), vy = OO(1, 3), vz = OO(1, 4);
    float wx = OO(2, 2), wy = OO(2, 3), wz = OO(2, 4);
    float Tt = OO(3, 1), Tx = OO(3, 2), Ty = OO(3, 3), Tz = OO(3, 4);

    float NSEu = OO(2, 6) - OO(1, 7)
               + u  * (OO(2, 9)  - OO(1, 10))
               + v_ * (OO(2, 11) - OO(1, 12))
               + w_ * (OO(2, 12) - OO(1, 13))
               - (wy - vz) * ux - (uz - wx) * uy - (vx - uy) * uz
               - S_C * (OO(2, 15) - OO(1, 16) + OO(2, 18) - OO(1, 19) + OO(2, 21) - OO(1, 22))
               - Ty;
    float NSEv = OO(0, 7) - OO(2, 5)
               + u  * (OO(0, 10) - OO(2, 8))
               + v_ * (OO(0, 12) - OO(2, 9))
               + w_ * (OO(0, 13) - OO(2, 10))
               - (wy - vz) * vx - (uz - wx) * vy - (vx - uy) * vz
               - S_C * (OO(0, 16) - OO(2, 14) + OO(0, 19) - OO(2, 17) + OO(0, 22) - OO(2, 20))
               + Tx;
    float NSEw = OO(1, 5) - OO(0, 6)
               + u  * (OO(1, 8)  - OO(0, 9))
               + v_ * (OO(1, 9)  - OO(0, 11))
               + w_ * (OO(1, 10) - OO(0, 12))
               - (wy - vz) * wx - (uz - wx) * wy - (vx - uy) * wz
               - S_C * (OO(1, 14) - OO(0, 15) + OO(1, 17) - OO(0, 18) + OO(1, 20) - OO(0, 21));

    float EE = Tt + u * Tx + v_ * Ty + w_ * Tz
             - KAP * (OO(3, 8) + OO(3, 11) + OO(3, 13));

    float conti = ux + vy + wz;
    const float* yt = y_true + ptt * 4;
    float d0 = u - yt[0], d1 = v_ - yt[1], d2 = w_ - yt[2];
    float dT = Ttrue - (OO(3, 23) + bo3);
#undef OO
    const float invN  = 1.0f / (float)NPTS;
    const float inv3N = 1.0f / (3.0f * (float)NPTS);
    float part = (d0 * d0 + d1 * d1 + d2 * d2) * inv3N
               + conti * conti * invN
               + (NSEu * NSEu + NSEv * NSEv + NSEw * NSEw) * inv3N
               + EE * EE * invN
               + dT * dT * invN;
    atomicAdd(out, part);
  }
}

extern "C" void kernel_launch(void* const* d_in, const int* in_sizes, int n_in,
                              void* d_out, int out_size, void* d_ws, size_t ws_size,
                              hipStream_t stream) {
  const float* inputs = (const float*)d_in[0];
  const float* y_true = (const float*)d_in[1];
  const float* W_in   = (const float*)d_in[2];
  const float* b_in   = (const float*)d_in[3];
  const float* W_hid  = (const float*)d_in[4];
  const float* b_hid  = (const float*)d_in[5];
  const float* W_out  = (const float*)d_in[6];
  const float* b_out  = (const float*)d_in[7];
  float* out = (float*)d_out;

  unsigned char* ws = (unsigned char*)d_ws;
  unsigned short* wshi = (unsigned short*)(ws);            // 163840 B
  unsigned short* wslo = (unsigned short*)(ws + 163840);   // 163840 B
  unsigned short* aohi = (unsigned short*)(ws + 327680);   // 4096 B
  unsigned short* aolo = (unsigned short*)(ws + 331776);   // 4096 B
  float4*         rnd  = (float4*)(ws + 335872);           // 65536 B

  hipMemsetAsync(out, 0, sizeof(float), stream);
  prep_kernel<<<344, 256, 0, stream>>>(W_hid, W_out, wshi, wslo, aohi, aolo, rnd);
  pinn_kernel<<<NPTS / PPB, BS, 0, stream>>>(inputs, y_true, W_in, b_in,
                                             b_hid, b_out,
                                             wshi, wslo, aohi, aolo, rnd, out);
}

// Round 5
// 146.219 us; speedup vs baseline: 2.3139x; 1.2310x over previous
//
#include <hip/hip_runtime.h>
#include <math.h>

#define NPTS 4096
#define DD   128
#define NCH  24
#define NHID 5
#define PPB  4            // points per block
#define BS   256
#define NJ   96           // jet rows (PPB*NCH)
#define RSU  280          // B row stride in ushorts (hi[128] lo[128] pad[24])
#define RS8  35           // B row stride in short8 units
#define RSW  140          // B row stride in u32 units
#define DST  132          // D row stride (floats), layout D[n][m]

typedef __attribute__((ext_vector_type(8))) short short8;
typedef __attribute__((ext_vector_type(4))) float f32x4;

// ---------------- bf16 helpers ----------------
static __device__ __forceinline__ unsigned short f2bf(float x) {
  unsigned u = __float_as_uint(x);
  unsigned r = (u + 0x7fffu + ((u >> 16) & 1u)) >> 16;   // RNE
  return (unsigned short)r;
}
static __device__ __forceinline__ float bf2f(unsigned short h) {
  return __uint_as_float(((unsigned)h) << 16);
}
// truncation split: x ~= hi + lo to ~2^-16 rel
static __device__ __forceinline__ void split_tr(float x, unsigned &hi,
                                                unsigned &lo) {
  unsigned u = __float_as_uint(x);
  hi = u >> 16;
  float rem = x - __uint_as_float(u & 0xffff0000u);
  lo = __float_as_uint(rem) >> 16;
}

// ---------------- threefry2x32 (matches JAX's PRNG) ----------------
static __device__ __forceinline__ void tf2x32(unsigned k0, unsigned k1,
                                              unsigned x0, unsigned x1,
                                              unsigned &o0, unsigned &o1) {
  unsigned ks2 = 0x1BD11BDAu ^ k0 ^ k1;
  x0 += k0; x1 += k1;
#define TFR(r) { x0 += x1; x1 = (x1 << (r)) | (x1 >> (32 - (r))); x1 ^= x0; }
  TFR(13) TFR(15) TFR(26) TFR(6)  x0 += k1;  x1 += ks2 + 1u;
  TFR(17) TFR(29) TFR(16) TFR(24) x0 += ks2; x1 += k0 + 2u;
  TFR(13) TFR(15) TFR(26) TFR(6)  x0 += k0;  x1 += k1 + 3u;
  TFR(17) TFR(29) TFR(16) TFR(24) x0 += k1;  x1 += ks2 + 4u;
  TFR(13) TFR(15) TFR(26) TFR(6)  x0 += ks2; x1 += k0 + 5u;
#undef TFR
  o0 = x0; o1 = x1;
}
static __device__ __forceinline__ float bits_to_unif(unsigned b) {
  return __uint_as_float((b >> 9) | 0x3f800000u) - 1.0f;
}
static __device__ __forceinline__ void bnd_rand(int pt, float &xb1, float &xb2,
                                                unsigned &zbit) {
  unsigned a0, a1, b0, b1;
  tf2x32(0u, 22u, 0u, 2u, a0, b0);
  tf2x32(0u, 22u, 1u, 3u, a1, b1);
  unsigned f0, f1, zf, o0_, o1_;
  unsigned jj0 = 2u * (unsigned)pt, jj1 = jj0 + 1u;
  if (jj0 < 4096u) { tf2x32(a0, a1, jj0,         jj0 + 4096u, o0_, o1_); f0 = o0_; }
  else             { tf2x32(a0, a1, jj0 - 4096u, jj0,         o0_, o1_); f0 = o1_; }
  if (jj1 < 4096u) { tf2x32(a0, a1, jj1,         jj1 + 4096u, o0_, o1_); f1 = o0_; }
  else             { tf2x32(a0, a1, jj1 - 4096u, jj1,         o0_, o1_); f1 = o1_; }
  if (pt < 2048)   { tf2x32(b0, b1, (unsigned)pt,         (unsigned)pt + 2048u, o0_, o1_); zf = o0_; }
  else             { tf2x32(b0, b1, (unsigned)pt - 2048u, (unsigned)pt,         o0_, o1_); zf = o1_; }
  xb1 = bits_to_unif(f0); xb2 = bits_to_unif(f1); zbit = zf & 1u;
}

// ---------------- jet composition through a = 0.5*sin(2*pi*h) ----------------
static __device__ __forceinline__ void activate_jet(float q[NCH]) {
  const float PI1 = 3.14159265358979323846f;
  float hr = q[0] - floorf(q[0]);
  float sv = __builtin_amdgcn_sinf(hr);
  float cv = __builtin_amdgcn_cosf(hr);
  float p1 = PI1 * cv;
  float p2 = -2.0f * PI1 * PI1 * sv;
  float p3 = -4.0f * PI1 * PI1 * PI1 * cv;
  float g0 = q[1], g1 = q[2], g2 = q[3], g3 = q[4];
  float s_tx = q[5], s_ty = q[6], s_tz = q[7], s_xx = q[8], s_xy = q[9],
        s_xz = q[10], s_yy = q[11], s_yz = q[12], s_zz = q[13];
  float T0 = q[14], T1 = q[15], T2 = q[16], T3 = q[17], T4 = q[18],
        T5 = q[19], T6 = q[20], T7 = q[21], T8 = q[22];
  q[0] = 0.5f * sv;
  q[1] = p1 * g0; q[2] = p1 * g1; q[3] = p1 * g2; q[4] = p1 * g3;
  q[5]  = p2 * g0 * g1 + p1 * s_tx;
  q[6]  = p2 * g0 * g2 + p1 * s_ty;
  q[7]  = p2 * g0 * g3 + p1 * s_tz;
  q[8]  = p2 * g1 * g1 + p1 * s_xx;
  q[9]  = p2 * g1 * g2 + p1 * s_xy;
  q[10] = p2 * g1 * g3 + p1 * s_xz;
  q[11] = p2 * g2 * g2 + p1 * s_yy;
  q[12] = p2 * g2 * g3 + p1 * s_yz;
  q[13] = p2 * g3 * g3 + p1 * s_zz;
  q[14] = p3 * g1 * g1 * g1 + p2 * (3.0f * s_xx * g1)             + p1 * T0;
  q[15] = p3 * g2 * g1 * g1 + p2 * (2.0f * s_xy * g1 + s_xx * g2) + p1 * T1;
  q[16] = p3 * g3 * g1 * g1 + p2 * (2.0f * s_xz * g1 + s_xx * g3) + p1 * T2;
  q[17] = p3 * g1 * g2 * g2 + p2 * (2.0f * s_xy * g2 + s_yy * g1) + p1 * T3;
  q[18] = p3 * g2 * g2 * g2 + p2 * (3.0f * s_yy * g2)             + p1 * T4;
  q[19] = p3 * g3 * g2 * g2 + p2 * (2.0f * s_yz * g2 + s_yy * g3) + p1 * T5;
  q[20] = p3 * g1 * g3 * g3 + p2 * (2.0f * s_xz * g3 + s_zz * g1) + p1 * T6;
  q[21] = p3 * g2 * g3 * g3 + p2 * (2.0f * s_yz * g3 + s_zz * g2) + p1 * T7;
  q[22] = p3 * g3 * g3 * g3 + p2 * (3.0f * s_zz * g3)             + p1 * T8;
  float br = q[23] - floorf(q[23]);
  q[23] = 0.5f * __builtin_amdgcn_sinf(br);
}

// k-permutation: neuron j lives at k_phys = 2*(j&63) + (j>>6)
// inverse: k_orig(k_phys) = (k_phys>>1) + ((k_phys&1)<<6)
// ---------------- prep: weight split (permuted layout) + RNG --------------
// wshi/wslo layout: [l][ks(4)][m(128)][quad(4)][e(8)]  (ushort)
// aohi/aolo layout: [ks(4)][m(16)][quad(4)][e(8)]
__global__ __launch_bounds__(256) void prep_kernel(
    const float* __restrict__ W_hid, const float* __restrict__ W_out,
    unsigned short* __restrict__ wshi, unsigned short* __restrict__ wslo,
    unsigned short* __restrict__ aohi, unsigned short* __restrict__ aolo,
    float4* __restrict__ rnd) {
  int b = blockIdx.x;
  if (b < 320) {
    int idx = b * 256 + threadIdx.x;
    int l = idx >> 14, r = idx & 16383;
    int ks = r >> 12, r2 = r & 4095;
    int m = r2 >> 5, r3 = r2 & 31;
    int kp = ks * 32 + r3;                         // quad*8+e = r3
    int ko = (kp >> 1) + ((kp & 1) << 6);
    float w = W_hid[(l << 14) + (ko << 7) + m];
    unsigned short hi = f2bf(w);
    wshi[idx] = hi; wslo[idx] = f2bf(w - bf2f(hi));
  } else if (b < 328) {
    int idx = (b - 320) * 256 + threadIdx.x;       // 0..2047
    int ks = idx >> 9, r2 = idx & 511;
    int m = r2 >> 5, r3 = r2 & 31;
    int kp = ks * 32 + r3;
    int ko = (kp >> 1) + ((kp & 1) << 6);
    float w = (m < 4) ? W_out[ko * 4 + m] : 0.0f;
    unsigned short hi = f2bf(w);
    aohi[idx] = hi; aolo[idx] = f2bf(w - bf2f(hi));
  } else {
    int pt = (b - 328) * 256 + threadIdx.x;
    float xb1, xb2; unsigned zbit;
    bnd_rand(pt, xb1, xb2, zbit);
    rnd[pt] = make_float4(xb1, xb2, (float)zbit, zbit ? -0.5f : 0.5f);
  }
}

// ---------------- main kernel ----------------
// LDS 53760 B: B = 96 rows x 560 B (hi[128]u16, lo[128]u16, pad).
// D aliases: float[96][DST=132] (50688 B). 4 barriers/layer.
// Wave grid 2M x 2N: wave (wm,wn) owns M-half 64, N-half 48.
__global__ __launch_bounds__(BS, 3) void pinn_kernel(
    const float* __restrict__ inputs, const float* __restrict__ y_true,
    const float* __restrict__ W_in,  const float* __restrict__ b_in,
    const float* __restrict__ b_hid, const float* __restrict__ b_out,
    const unsigned short* __restrict__ wshi,
    const unsigned short* __restrict__ wslo,
    const unsigned short* __restrict__ aohi,
    const unsigned short* __restrict__ aolo,
    const float4* __restrict__ rnd,
    float* __restrict__ out)
{
  __shared__ __align__(16) unsigned char smem[NJ * RSU * 2];
  unsigned* Bw = (unsigned*)smem;       // u32 view (packed hi|hi, lo|lo)
  float* Df = (float*)smem;             // D alias
  float* O0 = (float*)smem;             // output staging, rows 0..47
  float* O1 = (float*)(smem + 48 * RSU * 2);  // rows 48..95 (wave1's region)

  const int t    = threadIdx.x;
  const int wave = t >> 6;
  const int lane = t & 63;
  const int quad = lane >> 4;
  const int nl   = lane & 15;
  const int wm   = wave >> 1;
  const int wn   = wave & 1;
  const int pt0  = blockIdx.x * PPB;
  const int p    = t >> 6;              // epilogue point (0..3)
  const int j0   = t & 63;              // epilogue neuron pair (j0, j0+64)
  const int pt   = pt0 + p;

  // ---- layer 1 (4 -> 128): thread handles (p, j0) and (p, j0+64)
  {
    float4 rv = rnd[pt];
    float x_t = inputs[pt * 4 + 0], x_x = inputs[pt * 4 + 1];
    float x_y = inputs[pt * 4 + 2], x_z = inputs[pt * 4 + 3];
    float q0[NCH], q1[NCH];
#pragma unroll
    for (int h = 0; h < 2; ++h) {
      int jj = j0 + h * 64;
      float* q = h ? q1 : q0;
      float w0 = W_in[0 * DD + jj], w1 = W_in[1 * DD + jj],
            w2 = W_in[2 * DD + jj], w3 = W_in[3 * DD + jj];
      float bb = b_in[jj];
      q[0] = bb + x_t * w0 + x_x * w1 + x_y * w2 + x_z * w3;
      q[1] = w0; q[2] = w1; q[3] = w2; q[4] = w3;
#pragma unroll
      for (int c = 5; c < 23; ++c) q[c] = 0.0f;
      q[23] = bb + x_t * w0 + rv.x * w1 + rv.y * w2 + rv.z * w3;
      activate_jet(q);
    }
#pragma unroll
    for (int c = 0; c < NCH; ++c) {
      unsigned h0, l0, h1, l1;
      split_tr(q0[c], h0, l0);
      split_tr(q1[c], h1, l1);
      int base = (p * NCH + c) * RSW + j0;
      Bw[base]      = h0 | (h1 << 16);
      Bw[base + 64] = l0 | (l1 << 16);
    }
  }

  // ---- hidden layers: GEMM M=128 x N=96 x K=128, split-bf16 3-MFMA
  for (int l = 0; l < NHID; ++l) {
    __syncthreads();   // (1) B ready
    f32x4 acc[4][3];
#pragma unroll
    for (int mt = 0; mt < 4; ++mt)
#pragma unroll
      for (int nt = 0; nt < 3; ++nt) acc[mt][nt] = (f32x4)0.0f;

    const short8* pB   = (const short8*)smem;
    const short8* pAhi = ((const short8*)wshi) + (l << 11);
    const short8* pAlo = ((const short8*)wslo) + (l << 11);

#pragma unroll
    for (int ks = 0; ks < 4; ++ks) {
      short8 bh[3], bl[3], ah[4], al[4];
#pragma unroll
      for (int nt = 0; nt < 3; ++nt) {
        int bidx = (wn * 48 + nt * 16 + nl) * RS8 + ks * 4 + quad;
        bh[nt] = pB[bidx];
        bl[nt] = pB[bidx + 16];
      }
#pragma unroll
      for (int mt = 0; mt < 4; ++mt) {
        int m = wm * 64 + mt * 16 + nl;
        int aidx = ks * 512 + m * 4 + quad;
        ah[mt] = pAhi[aidx];
        al[mt] = pAlo[aidx];
      }
#pragma unroll
      for (int mt = 0; mt < 4; ++mt)
#pragma unroll
        for (int nt = 0; nt < 3; ++nt) {
          acc[mt][nt] = __builtin_amdgcn_mfma_f32_16x16x32_bf16(ah[mt], bh[nt], acc[mt][nt], 0, 0, 0);
          acc[mt][nt] = __builtin_amdgcn_mfma_f32_16x16x32_bf16(ah[mt], bl[nt], acc[mt][nt], 0, 0, 0);
          acc[mt][nt] = __builtin_amdgcn_mfma_f32_16x16x32_bf16(al[mt], bh[nt], acc[mt][nt], 0, 0, 0);
        }
    }
    __syncthreads();   // (2) B reads done; D may overwrite

#pragma unroll
    for (int mt = 0; mt < 4; ++mt)
#pragma unroll
      for (int nt = 0; nt < 3; ++nt) {
        int n  = wn * 48 + nt * 16 + nl;
        int mb = wm * 64 + mt * 16 + (quad << 2);
        *(f32x4*)(Df + n * DST + mb) = acc[mt][nt];
      }
    __syncthreads();   // (3) D complete

    float q0[NCH], q1[NCH];
#pragma unroll
    for (int c = 0; c < NCH; ++c) {
      q0[c] = Df[(p * NCH + c) * DST + j0];
      q1[c] = Df[(p * NCH + c) * DST + j0 + 64];
    }
    __syncthreads();   // (4) D reads done; B may overwrite

    float b0 = b_hid[l * DD + j0];
    float b1 = b_hid[l * DD + j0 + 64];
    q0[0] += b0; q0[23] += b0;
    q1[0] += b1; q1[23] += b1;
    activate_jet(q0);
    activate_jet(q1);
#pragma unroll
    for (int c = 0; c < NCH; ++c) {
      unsigned h0, l0, h1, l1;
      split_tr(q0[c], h0, l0);
      split_tr(q1[c], h1, l1);
      int base = (p * NCH + c) * RSW + j0;
      Bw[base]      = h0 | (h1 << 16);
      Bw[base + 64] = l0 | (l1 << 16);
    }
  }
  __syncthreads();     // final jets ready

  // ---- output layer: padded M=16 GEMM, waves 0 (rows 0..47) & 1 (48..95).
  // Each wave writes O into its OWN B-read region -> same-wave dep only.
  if (wave < 2) {
    f32x4 acc2[3];
#pragma unroll
    for (int nt = 0; nt < 3; ++nt) acc2[nt] = (f32x4)0.0f;
    const short8* pB = (const short8*)smem;
    const short8* pAh = (const short8*)aohi;
    const short8* pAl = (const short8*)aolo;
#pragma unroll
    for (int ks = 0; ks < 4; ++ks) {
      short8 bh[3], bl[3];
#pragma unroll
      for (int nt = 0; nt < 3; ++nt) {
        int bidx = (wave * 48 + nt * 16 + nl) * RS8 + ks * 4 + quad;
        bh[nt] = pB[bidx];
        bl[nt] = pB[bidx + 16];
      }
      short8 ah = pAh[ks * 64 + nl * 4 + quad];
      short8 al = pAl[ks * 64 + nl * 4 + quad];
#pragma unroll
      for (int nt = 0; nt < 3; ++nt) {
        acc2[nt] = __builtin_amdgcn_mfma_f32_16x16x32_bf16(ah, bh[nt], acc2[nt], 0, 0, 0);
        acc2[nt] = __builtin_amdgcn_mfma_f32_16x16x32_bf16(ah, bl[nt], acc2[nt], 0, 0, 0);
        acc2[nt] = __builtin_amdgcn_mfma_f32_16x16x32_bf16(al, bh[nt], acc2[nt], 0, 0, 0);
      }
    }
    if (quad == 0) {      // m = 0..3 are the 4 real outputs
      float* Ox = wave ? O1 : O0;
#pragma unroll
      for (int nt = 0; nt < 3; ++nt) {
        int nloc = nt * 16 + nl;            // row within this wave's half
        *(f32x4*)(Ox + nloc * 4) = acc2[nt];
      }
    }
  }
  __syncthreads();     // O ready

  // ---- loss epilogue: threads 0..3 (one point each)
  if (t < PPB) {
    const int pp = t;
    const int ptt = pt0 + pp;
    const float Ttrue = rnd[ptt].w;
    const float S_C = 8.36660026534e-04f;   // sqrt(0.7/1e6)
    const float KAP = 1.19522860933e-03f;   // sqrt(1/(0.7*1e6))
    float bo0 = b_out[0], bo1 = b_out[1], bo2 = b_out[2], bo3 = b_out[3];
#define OO(o, c) ((pp * NCH + (c)) < 48 ? O0[(pp * NCH + (c)) * 4 + (o)] \
                                        : O1[(pp * NCH + (c) - 48) * 4 + (o)])
    float u  = OO(0, 0) + bo0, v_ = OO(1, 0) + bo1, w_ = OO(2, 0) + bo2;
    float ux = OO(0, 2), uy = OO(0, 3), uz = OO(0, 4);
    float vx = OO(1, 2), vy = OO(1, 3), vz = OO(1, 4);
    float wx = OO(2, 2), wy = OO(2, 3), wz = OO(2, 4);
    float Tt = OO(3, 1), Tx = OO(3, 2), Ty = OO(3, 3), Tz = OO(3, 4);

    float NSEu = OO(2, 6) - OO(1, 7)
               + u  * (OO(2, 9)  - OO(1, 10))
               + v_ * (OO(2, 11) - OO(1, 12))
               + w_ * (OO(2, 12) - OO(1, 13))
               - (wy - vz) * ux - (uz - wx) * uy - (vx - uy) * uz
               - S_C * (OO(2, 15) - OO(1, 16) + OO(2, 18) - OO(1, 19) + OO(2, 21) - OO(1, 22))
               - Ty;
    float NSEv = OO(0, 7) - OO(2, 5)
               + u  * (OO(0, 10) - OO(2, 8))
               + v_ * (OO(0, 12) - OO(2, 9))
               + w_ * (OO(0, 13) - OO(2, 10))
               - (wy - vz) * vx - (uz - wx) * vy - (vx - uy) * vz
               - S_C * (OO(0, 16) - OO(2, 14) + OO(0, 19) - OO(2, 17) + OO(0, 22) - OO(2, 20))
               + Tx;
    float NSEw = OO(1, 5) - OO(0, 6)
               + u  * (OO(1, 8)  - OO(0, 9))
               + v_ * (OO(1, 9)  - OO(0, 11))
               + w_ * (OO(1, 10) - OO(0, 12))
               - (wy - vz) * wx - (uz - wx) * wy - (vx - uy) * wz
               - S_C * (OO(1, 14) - OO(0, 15) + OO(1, 17) - OO(0, 18) + OO(1, 20) - OO(0, 21));

    float EE = Tt + u * Tx + v_ * Ty + w_ * Tz
             - KAP * (OO(3, 8) + OO(3, 11) + OO(3, 13));

    float conti = ux + vy + wz;
    const float* yt = y_true + ptt * 4;
    float d0 = u - yt[0], d1 = v_ - yt[1], d2 = w_ - yt[2];
    float dT = Ttrue - (OO(3, 23) + bo3);
#undef OO
    const float invN  = 1.0f / (float)NPTS;
    const float inv3N = 1.0f / (3.0f * (float)NPTS);
    float part = (d0 * d0 + d1 * d1 + d2 * d2) * inv3N
               + conti * conti * invN
               + (NSEu * NSEu + NSEv * NSEv + NSEw * NSEw) * inv3N
               + EE * EE * invN
               + dT * dT * invN;
    atomicAdd(out, part);
  }
}

extern "C" void kernel_launch(void* const* d_in, const int* in_sizes, int n_in,
                              void* d_out, int out_size, void* d_ws, size_t ws_size,
                              hipStream_t stream) {
  const float* inputs = (const float*)d_in[0];
  const float* y_true = (const float*)d_in[1];
  const float* W_in   = (const float*)d_in[2];
  const float* b_in   = (const float*)d_in[3];
  const float* W_hid  = (const float*)d_in[4];
  const float* b_hid  = (const float*)d_in[5];
  const float* W_out  = (const float*)d_in[6];
  const float* b_out  = (const float*)d_in[7];
  float* out = (float*)d_out;

  unsigned char* ws = (unsigned char*)d_ws;
  unsigned short* wshi = (unsigned short*)(ws);            // 163840 B
  unsigned short* wslo = (unsigned short*)(ws + 163840);   // 163840 B
  unsigned short* aohi = (unsigned short*)(ws + 327680);   // 4096 B
  unsigned short* aolo = (unsigned short*)(ws + 331776);   // 4096 B
  float4*         rnd  = (float4*)(ws + 335872);           // 65536 B

  hipMemsetAsync(out, 0, sizeof(float), stream);
  prep_kernel<<<344, 256, 0, stream>>>(W_hid, W_out, wshi, wslo, aohi, aolo, rnd);
  pinn_kernel<<<NPTS / PPB, BS, 0, stream>>>(inputs, y_true, W_in, b_in,
                                             b_hid, b_out,
                                             wshi, wslo, aohi, aolo, rnd, out);
}

// Round 6
// 145.864 us; speedup vs baseline: 2.3196x; 1.0024x over previous
//
#include <hip/hip_runtime.h>
#include <math.h>

#define NPTS 4096
#define DD   128
#define NCH  24
#define NHID 5
#define PPB  2            // points per block
#define BS   128          // 2 waves
#define NJ   48           // jet rows (PPB*NCH)
#define RSU  280          // B row stride in ushorts (hi[128] lo[128] pad[24])
#define RS8  35           // B row stride in short8 units
#define RSW  140          // B row stride in u32 units
#define DST  132          // D row stride (floats), layout D[n][m]

typedef __attribute__((ext_vector_type(8))) short short8;
typedef __attribute__((ext_vector_type(4))) float f32x4;

// ---------------- bf16 helpers ----------------
static __device__ __forceinline__ unsigned short f2bf(float x) {
  unsigned u = __float_as_uint(x);
  unsigned r = (u + 0x7fffu + ((u >> 16) & 1u)) >> 16;   // RNE
  return (unsigned short)r;
}
static __device__ __forceinline__ float bf2f(unsigned short h) {
  return __uint_as_float(((unsigned)h) << 16);
}
// truncation split: x ~= hi + lo to ~2^-16 rel
static __device__ __forceinline__ void split_tr(float x, unsigned &hi,
                                                unsigned &lo) {
  unsigned u = __float_as_uint(x);
  hi = u >> 16;
  float rem = x - __uint_as_float(u & 0xffff0000u);
  lo = __float_as_uint(rem) >> 16;
}

// ---------------- threefry2x32 (matches JAX's PRNG) ----------------
static __device__ __forceinline__ void tf2x32(unsigned k0, unsigned k1,
                                              unsigned x0, unsigned x1,
                                              unsigned &o0, unsigned &o1) {
  unsigned ks2 = 0x1BD11BDAu ^ k0 ^ k1;
  x0 += k0; x1 += k1;
#define TFR(r) { x0 += x1; x1 = (x1 << (r)) | (x1 >> (32 - (r))); x1 ^= x0; }
  TFR(13) TFR(15) TFR(26) TFR(6)  x0 += k1;  x1 += ks2 + 1u;
  TFR(17) TFR(29) TFR(16) TFR(24) x0 += ks2; x1 += k0 + 2u;
  TFR(13) TFR(15) TFR(26) TFR(6)  x0 += k0;  x1 += k1 + 3u;
  TFR(17) TFR(29) TFR(16) TFR(24) x0 += k1;  x1 += ks2 + 4u;
  TFR(13) TFR(15) TFR(26) TFR(6)  x0 += ks2; x1 += k0 + 5u;
#undef TFR
  o0 = x0; o1 = x1;
}
static __device__ __forceinline__ float bits_to_unif(unsigned b) {
  return __uint_as_float((b >> 9) | 0x3f800000u) - 1.0f;
}
static __device__ __forceinline__ void bnd_rand(int pt, float &xb1, float &xb2,
                                                unsigned &zbit) {
  unsigned a0, a1, b0, b1;
  tf2x32(0u, 22u, 0u, 2u, a0, b0);
  tf2x32(0u, 22u, 1u, 3u, a1, b1);
  unsigned f0, f1, zf, o0_, o1_;
  unsigned jj0 = 2u * (unsigned)pt, jj1 = jj0 + 1u;
  if (jj0 < 4096u) { tf2x32(a0, a1, jj0,         jj0 + 4096u, o0_, o1_); f0 = o0_; }
  else             { tf2x32(a0, a1, jj0 - 4096u, jj0,         o0_, o1_); f0 = o1_; }
  if (jj1 < 4096u) { tf2x32(a0, a1, jj1,         jj1 + 4096u, o0_, o1_); f1 = o0_; }
  else             { tf2x32(a0, a1, jj1 - 4096u, jj1,         o0_, o1_); f1 = o1_; }
  if (pt < 2048)   { tf2x32(b0, b1, (unsigned)pt,         (unsigned)pt + 2048u, o0_, o1_); zf = o0_; }
  else             { tf2x32(b0, b1, (unsigned)pt - 2048u, (unsigned)pt,         o0_, o1_); zf = o1_; }
  xb1 = bits_to_unif(f0); xb2 = bits_to_unif(f1); zbit = zf & 1u;
}

// ---------------- jet composition through a = 0.5*sin(2*pi*h) ----------------
static __device__ __forceinline__ void activate_jet(float q[NCH]) {
  const float PI1 = 3.14159265358979323846f;
  float hr = q[0] - floorf(q[0]);
  float sv = __builtin_amdgcn_sinf(hr);
  float cv = __builtin_amdgcn_cosf(hr);
  float p1 = PI1 * cv;
  float p2 = -2.0f * PI1 * PI1 * sv;
  float p3 = -4.0f * PI1 * PI1 * PI1 * cv;
  float g0 = q[1], g1 = q[2], g2 = q[3], g3 = q[4];
  float s_tx = q[5], s_ty = q[6], s_tz = q[7], s_xx = q[8], s_xy = q[9],
        s_xz = q[10], s_yy = q[11], s_yz = q[12], s_zz = q[13];
  float T0 = q[14], T1 = q[15], T2 = q[16], T3 = q[17], T4 = q[18],
        T5 = q[19], T6 = q[20], T7 = q[21], T8 = q[22];
  q[0] = 0.5f * sv;
  q[1] = p1 * g0; q[2] = p1 * g1; q[3] = p1 * g2; q[4] = p1 * g3;
  q[5]  = p2 * g0 * g1 + p1 * s_tx;
  q[6]  = p2 * g0 * g2 + p1 * s_ty;
  q[7]  = p2 * g0 * g3 + p1 * s_tz;
  q[8]  = p2 * g1 * g1 + p1 * s_xx;
  q[9]  = p2 * g1 * g2 + p1 * s_xy;
  q[10] = p2 * g1 * g3 + p1 * s_xz;
  q[11] = p2 * g2 * g2 + p1 * s_yy;
  q[12] = p2 * g2 * g3 + p1 * s_yz;
  q[13] = p2 * g3 * g3 + p1 * s_zz;
  q[14] = p3 * g1 * g1 * g1 + p2 * (3.0f * s_xx * g1)             + p1 * T0;
  q[15] = p3 * g2 * g1 * g1 + p2 * (2.0f * s_xy * g1 + s_xx * g2) + p1 * T1;
  q[16] = p3 * g3 * g1 * g1 + p2 * (2.0f * s_xz * g1 + s_xx * g3) + p1 * T2;
  q[17] = p3 * g1 * g2 * g2 + p2 * (2.0f * s_xy * g2 + s_yy * g1) + p1 * T3;
  q[18] = p3 * g2 * g2 * g2 + p2 * (3.0f * s_yy * g2)             + p1 * T4;
  q[19] = p3 * g3 * g2 * g2 + p2 * (2.0f * s_yz * g2 + s_yy * g3) + p1 * T5;
  q[20] = p3 * g1 * g3 * g3 + p2 * (2.0f * s_xz * g3 + s_zz * g1) + p1 * T6;
  q[21] = p3 * g2 * g3 * g3 + p2 * (2.0f * s_yz * g3 + s_zz * g2) + p1 * T7;
  q[22] = p3 * g3 * g3 * g3 + p2 * (3.0f * s_zz * g3)             + p1 * T8;
  float br = q[23] - floorf(q[23]);
  q[23] = 0.5f * __builtin_amdgcn_sinf(br);
}

// k-permutation: neuron j lives at k_phys = 2*(j&63) + (j>>6)
// inverse: k_orig(k_phys) = (k_phys>>1) + ((k_phys&1)<<6)
// ---------------- prep: weight split (permuted layout) + RNG + out=0 ------
// wshi/wslo layout: [l][ks(4)][m(128)][quad(4)][e(8)]  (ushort)
// aohi/aolo layout: [ks(4)][m(16)][quad(4)][e(8)]
__global__ __launch_bounds__(256) void prep_kernel(
    const float* __restrict__ W_hid, const float* __restrict__ W_out,
    unsigned short* __restrict__ wshi, unsigned short* __restrict__ wslo,
    unsigned short* __restrict__ aohi, unsigned short* __restrict__ aolo,
    float4* __restrict__ rnd, float* __restrict__ out) {
  int b = blockIdx.x;
  if (b == 0 && threadIdx.x == 0) out[0] = 0.0f;
  if (b < 320) {
    int idx = b * 256 + threadIdx.x;
    int l = idx >> 14, r = idx & 16383;
    int ks = r >> 12, r2 = r & 4095;
    int m = r2 >> 5, r3 = r2 & 31;
    int kp = ks * 32 + r3;                         // quad*8+e = r3
    int ko = (kp >> 1) + ((kp & 1) << 6);
    float w = W_hid[(l << 14) + (ko << 7) + m];
    unsigned short hi = f2bf(w);
    wshi[idx] = hi; wslo[idx] = f2bf(w - bf2f(hi));
  } else if (b < 328) {
    int idx = (b - 320) * 256 + threadIdx.x;       // 0..2047
    int ks = idx >> 9, r2 = idx & 511;
    int m = r2 >> 5, r3 = r2 & 31;
    int kp = ks * 32 + r3;
    int ko = (kp >> 1) + ((kp & 1) << 6);
    float w = (m < 4) ? W_out[ko * 4 + m] : 0.0f;
    unsigned short hi = f2bf(w);
    aohi[idx] = hi; aolo[idx] = f2bf(w - bf2f(hi));
  } else {
    int pt = (b - 328) * 256 + threadIdx.x;
    float xb1, xb2; unsigned zbit;
    bnd_rand(pt, xb1, xb2, zbit);
    rnd[pt] = make_float4(xb1, xb2, (float)zbit, zbit ? -0.5f : 0.5f);
  }
}

// ---------------- main kernel ----------------
// LDS 26880 B: B = 48 rows x 560 B (hi[128]u16 | lo[128]u16 | pad).
// D aliases: float[48][DST=132] (25344 B). O (192 floats) aliases B start.
// 2 waves: wave = M-half (64 neurons). 4 barriers/layer, 6 blocks/CU.
__global__ __launch_bounds__(BS, 3) void pinn_kernel(
    const float* __restrict__ inputs, const float* __restrict__ y_true,
    const float* __restrict__ W_in,  const float* __restrict__ b_in,
    const float* __restrict__ b_hid, const float* __restrict__ b_out,
    const unsigned short* __restrict__ wshi,
    const unsigned short* __restrict__ wslo,
    const unsigned short* __restrict__ aohi,
    const unsigned short* __restrict__ aolo,
    const float4* __restrict__ rnd,
    float* __restrict__ out)
{
  __shared__ __align__(16) unsigned char smem[NJ * RSU * 2];
  unsigned* Bw = (unsigned*)smem;       // u32 view (packed hi|hi, lo|lo)
  float* Df = (float*)smem;             // D alias
  float* Osm = (float*)smem;            // output staging alias (48 x 4 f32)

  const int t    = threadIdx.x;
  const int wave = t >> 6;              // = wm (M-half)
  const int lane = t & 63;
  const int quad = lane >> 4;
  const int nl   = lane & 15;
  const int pt0  = blockIdx.x * PPB;
  const int p    = t >> 6;              // epilogue point (0..1)
  const int j0   = t & 63;              // epilogue neuron pair (j0, j0+64)
  const int pt   = pt0 + p;

  // ---- layer 1 (4 -> 128): thread handles (p, j0) and (p, j0+64)
  {
    float4 rv = rnd[pt];
    float x_t = inputs[pt * 4 + 0], x_x = inputs[pt * 4 + 1];
    float x_y = inputs[pt * 4 + 2], x_z = inputs[pt * 4 + 3];
    float q0[NCH], q1[NCH];
#pragma unroll
    for (int h = 0; h < 2; ++h) {
      int jj = j0 + h * 64;
      float* q = h ? q1 : q0;
      float w0 = W_in[0 * DD + jj], w1 = W_in[1 * DD + jj],
            w2 = W_in[2 * DD + jj], w3 = W_in[3 * DD + jj];
      float bb = b_in[jj];
      q[0] = bb + x_t * w0 + x_x * w1 + x_y * w2 + x_z * w3;
      q[1] = w0; q[2] = w1; q[3] = w2; q[4] = w3;
#pragma unroll
      for (int c = 5; c < 23; ++c) q[c] = 0.0f;
      q[23] = bb + x_t * w0 + rv.x * w1 + rv.y * w2 + rv.z * w3;
      activate_jet(q);
    }
#pragma unroll
    for (int c = 0; c < NCH; ++c) {
      unsigned h0, l0, h1, l1;
      split_tr(q0[c], h0, l0);
      split_tr(q1[c], h1, l1);
      int base = (p * NCH + c) * RSW + j0;
      Bw[base]      = h0 | (h1 << 16);
      Bw[base + 64] = l0 | (l1 << 16);
    }
  }

  // ---- hidden layers: GEMM M=128 x N=48 x K=128, split-bf16 3-MFMA
  for (int l = 0; l < NHID; ++l) {
    __syncthreads();   // (1) B ready
    f32x4 acc[4][3];
#pragma unroll
    for (int mt = 0; mt < 4; ++mt)
#pragma unroll
      for (int nt = 0; nt < 3; ++nt) acc[mt][nt] = (f32x4)0.0f;

    const short8* pB   = (const short8*)smem;
    const short8* pAhi = ((const short8*)wshi) + (l << 11);
    const short8* pAlo = ((const short8*)wslo) + (l << 11);

#pragma unroll
    for (int ks = 0; ks < 4; ++ks) {
      short8 bh[3], bl[3], ah[4], al[4];
#pragma unroll
      for (int nt = 0; nt < 3; ++nt) {
        int bidx = (nt * 16 + nl) * RS8 + ks * 4 + quad;
        bh[nt] = pB[bidx];
        bl[nt] = pB[bidx + 16];
      }
#pragma unroll
      for (int mt = 0; mt < 4; ++mt) {
        int m = wave * 64 + mt * 16 + nl;
        int aidx = ks * 512 + m * 4 + quad;
        ah[mt] = pAhi[aidx];
        al[mt] = pAlo[aidx];
      }
#pragma unroll
      for (int mt = 0; mt < 4; ++mt)
#pragma unroll
        for (int nt = 0; nt < 3; ++nt) {
          acc[mt][nt] = __builtin_amdgcn_mfma_f32_16x16x32_bf16(ah[mt], bh[nt], acc[mt][nt], 0, 0, 0);
          acc[mt][nt] = __builtin_amdgcn_mfma_f32_16x16x32_bf16(ah[mt], bl[nt], acc[mt][nt], 0, 0, 0);
          acc[mt][nt] = __builtin_amdgcn_mfma_f32_16x16x32_bf16(al[mt], bh[nt], acc[mt][nt], 0, 0, 0);
        }
    }
    __syncthreads();   // (2) B reads done; D may overwrite

#pragma unroll
    for (int mt = 0; mt < 4; ++mt)
#pragma unroll
      for (int nt = 0; nt < 3; ++nt) {
        int n  = nt * 16 + nl;
        int mb = wave * 64 + mt * 16 + (quad << 2);
        *(f32x4*)(Df + n * DST + mb) = acc[mt][nt];
      }
    __syncthreads();   // (3) D complete

    float q0[NCH], q1[NCH];
#pragma unroll
    for (int c = 0; c < NCH; ++c) {
      q0[c] = Df[(p * NCH + c) * DST + j0];
      q1[c] = Df[(p * NCH + c) * DST + j0 + 64];
    }
    __syncthreads();   // (4) D reads done; B may overwrite

    float b0 = b_hid[l * DD + j0];
    float b1 = b_hid[l * DD + j0 + 64];
    q0[0] += b0; q0[23] += b0;
    q1[0] += b1; q1[23] += b1;
    activate_jet(q0);
    activate_jet(q1);
#pragma unroll
    for (int c = 0; c < NCH; ++c) {
      unsigned h0, l0, h1, l1;
      split_tr(q0[c], h0, l0);
      split_tr(q1[c], h1, l1);
      int base = (p * NCH + c) * RSW + j0;
      Bw[base]      = h0 | (h1 << 16);
      Bw[base + 64] = l0 | (l1 << 16);
    }
  }
  __syncthreads();     // final jets ready

  // ---- output layer: padded M=16 GEMM. wave0: nt 0,1; wave1: nt 2.
  {
    const int ntl = wave == 0 ? 2 : 1;
    const int nt0 = wave == 0 ? 0 : 2;
    f32x4 acc2[2];
#pragma unroll
    for (int i = 0; i < 2; ++i) acc2[i] = (f32x4)0.0f;
    const short8* pB = (const short8*)smem;
    const short8* pAh = (const short8*)aohi;
    const short8* pAl = (const short8*)aolo;
#pragma unroll
    for (int ks = 0; ks < 4; ++ks) {
      short8 ah = pAh[ks * 64 + nl * 4 + quad];
      short8 al = pAl[ks * 64 + nl * 4 + quad];
      for (int i = 0; i < ntl; ++i) {
        int nt = nt0 + i;
        int bidx = (nt * 16 + nl) * RS8 + ks * 4 + quad;
        short8 bh = pB[bidx];
        short8 bl = pB[bidx + 16];
        acc2[i] = __builtin_amdgcn_mfma_f32_16x16x32_bf16(ah, bh, acc2[i], 0, 0, 0);
        acc2[i] = __builtin_amdgcn_mfma_f32_16x16x32_bf16(ah, bl, acc2[i], 0, 0, 0);
        acc2[i] = __builtin_amdgcn_mfma_f32_16x16x32_bf16(al, bh, acc2[i], 0, 0, 0);
      }
    }
    __syncthreads();   // all B reads done; Osm may overwrite B start
    if (quad == 0) {
      for (int i = 0; i < ntl; ++i) {
        int n = (nt0 + i) * 16 + nl;
        *(f32x4*)(Osm + n * 4) = acc2[i];   // rows m=0..3 = outputs
      }
    }
  }
  __syncthreads();     // O ready

  // ---- loss epilogue: threads 0..1 (one point each)
  if (t < PPB) {
    const int pp = t;
    const int ptt = pt0 + pp;
    const float Ttrue = rnd[ptt].w;
    const float S_C = 8.36660026534e-04f;   // sqrt(0.7/1e6)
    const float KAP = 1.19522860933e-03f;   // sqrt(1/(0.7*1e6))
    float bo0 = b_out[0], bo1 = b_out[1], bo2 = b_out[2], bo3 = b_out[3];
#define OO(o, c) Osm[(pp * NCH + (c)) * 4 + (o)]
    float u  = OO(0, 0) + bo0, v_ = OO(1, 0) + bo1, w_ = OO(2, 0) + bo2;
    float ux = OO(0, 2), uy = OO(0, 3), uz = OO(0, 4);
    float vx = OO(1, 2), vy = OO(1, 3), vz = OO(1, 4);
    float wx = OO(2, 2), wy = OO(2, 3), wz = OO(2, 4);
    float Tt = OO(3, 1), Tx = OO(3, 2), Ty = OO(3, 3), Tz = OO(3, 4);

    float NSEu = OO(2, 6) - OO(1, 7)
               + u  * (OO(2, 9)  - OO(1, 10))
               + v_ * (OO(2, 11) - OO(1, 12))
               + w_ * (OO(2, 12) - OO(1, 13))
               - (wy - vz) * ux - (uz - wx) * uy - (vx - uy) * uz
               - S_C * (OO(2, 15) - OO(1, 16) + OO(2, 18) - OO(1, 19) + OO(2, 21) - OO(1, 22))
               - Ty;
    float NSEv = OO(0, 7) - OO(2, 5)
               + u  * (OO(0, 10) - OO(2, 8))
               + v_ * (OO(0, 12) - OO(2, 9))
               + w_ * (OO(0, 13) - OO(2, 10))
               - (wy - vz) * vx - (uz - wx) * vy - (vx - uy) * vz
               - S_C * (OO(0, 16) - OO(2, 14) + OO(0, 19) - OO(2, 17) + OO(0, 22) - OO(2, 20))
               + Tx;
    float NSEw = OO(1, 5) - OO(0, 6)
               + u  * (OO(1, 8)  - OO(0, 9))
               + v_ * (OO(1, 9)  - OO(0, 11))
               + w_ * (OO(1, 10) - OO(0, 12))
               - (wy - vz) * wx - (uz - wx) * wy - (vx - uy) * wz
               - S_C * (OO(1, 14) - OO(0, 15) + OO(1, 17) - OO(0, 18) + OO(1, 20) - OO(0, 21));

    float EE = Tt + u * Tx + v_ * Ty + w_ * Tz
             - KAP * (OO(3, 8) + OO(3, 11) + OO(3, 13));

    float conti = ux + vy + wz;
    const float* yt = y_true + ptt * 4;
    float d0 = u - yt[0], d1 = v_ - yt[1], d2 = w_ - yt[2];
    float dT = Ttrue - (OO(3, 23) + bo3);
#undef OO
    const float invN  = 1.0f / (float)NPTS;
    const float inv3N = 1.0f / (3.0f * (float)NPTS);
    float part = (d0 * d0 + d1 * d1 + d2 * d2) * inv3N
               + conti * conti * invN
               + (NSEu * NSEu + NSEv * NSEv + NSEw * NSEw) * inv3N
               + EE * EE * invN
               + dT * dT * invN;
    atomicAdd(out, part);
  }
}

extern "C" void kernel_launch(void* const* d_in, const int* in_sizes, int n_in,
                              void* d_out, int out_size, void* d_ws, size_t ws_size,
                              hipStream_t stream) {
  const float* inputs = (const float*)d_in[0];
  const float* y_true = (const float*)d_in[1];
  const float* W_in   = (const float*)d_in[2];
  const float* b_in   = (const float*)d_in[3];
  const float* W_hid  = (const float*)d_in[4];
  const float* b_hid  = (const float*)d_in[5];
  const float* W_out  = (const float*)d_in[6];
  const float* b_out  = (const float*)d_in[7];
  float* out = (float*)d_out;

  unsigned char* ws = (unsigned char*)d_ws;
  unsigned short* wshi = (unsigned short*)(ws);            // 163840 B
  unsigned short* wslo = (unsigned short*)(ws + 163840);   // 163840 B
  unsigned short* aohi = (unsigned short*)(ws + 327680);   // 4096 B
  unsigned short* aolo = (unsigned short*)(ws + 331776);   // 4096 B
  float4*         rnd  = (float4*)(ws + 335872);           // 65536 B

  prep_kernel<<<344, 256, 0, stream>>>(W_hid, W_out, wshi, wslo, aohi, aolo,
                                       rnd, out);
  pinn_kernel<<<NPTS / PPB, BS, 0, stream>>>(inputs, y_true, W_in, b_in,
                                             b_hid, b_out,
                                             wshi, wslo, aohi, aolo, rnd, out);
}

// Round 8
// 138.126 us; speedup vs baseline: 2.4495x; 1.0560x over previous
//
#include <hip/hip_runtime.h>
#include <math.h>

#define NPTS 4096
#define DD   128
#define NCH  24
#define NHID 5
#define PPB  4            // points per block
#define BS   256
#define NJ   96           // jet rows (PPB*NCH)
#define RSU  136          // B row stride in ushorts (fp16[128] + pad 8)
#define RS8  17           // B row stride in half8 units
#define RSW  68           // B row stride in u32 units
#define DST  132          // D row stride (floats), layout D[n][m]
#define OSM_OFF 26112     // Osm staging offset (dead D region after B end)

typedef __attribute__((ext_vector_type(8))) _Float16 half8;
typedef __attribute__((ext_vector_type(4))) float f32x4;

// channel scales: ch0-4,23: 1; ch5-13 (2nd): 2^-10; ch14-22 (3rd): 2^-16
#define SS_INV 1024.0f
#define ST_INV 65536.0f

static __device__ __forceinline__ unsigned short f2h_bits(float x) {
  _Float16 h = (_Float16)x;            // RNE
  unsigned short u; __builtin_memcpy(&u, &h, 2); return u;
}
static __device__ __forceinline__ float h2f(unsigned short u) {
  _Float16 h; __builtin_memcpy(&h, &u, 2); return (float)h;
}
static __device__ __forceinline__ unsigned pk2(float a, float b) {
  return (unsigned)f2h_bits(a) | ((unsigned)f2h_bits(b) << 16);
}

// ---------------- threefry2x32 (matches JAX's PRNG) ----------------
static __device__ __forceinline__ void tf2x32(unsigned k0, unsigned k1,
                                              unsigned x0, unsigned x1,
                                              unsigned &o0, unsigned &o1) {
  unsigned ks2 = 0x1BD11BDAu ^ k0 ^ k1;
  x0 += k0; x1 += k1;
#define TFR(r) { x0 += x1; x1 = (x1 << (r)) | (x1 >> (32 - (r))); x1 ^= x0; }
  TFR(13) TFR(15) TFR(26) TFR(6)  x0 += k1;  x1 += ks2 + 1u;
  TFR(17) TFR(29) TFR(16) TFR(24) x0 += ks2; x1 += k0 + 2u;
  TFR(13) TFR(15) TFR(26) TFR(6)  x0 += k0;  x1 += k1 + 3u;
  TFR(17) TFR(29) TFR(16) TFR(24) x0 += k1;  x1 += ks2 + 4u;
  TFR(13) TFR(15) TFR(26) TFR(6)  x0 += ks2; x1 += k0 + 5u;
#undef TFR
  o0 = x0; o1 = x1;
}
static __device__ __forceinline__ float bits_to_unif(unsigned b) {
  return __uint_as_float((b >> 9) | 0x3f800000u) - 1.0f;
}
static __device__ __forceinline__ void bnd_rand(int pt, float &xb1, float &xb2,
                                                unsigned &zbit) {
  unsigned a0, a1, b0, b1;
  tf2x32(0u, 22u, 0u, 2u, a0, b0);
  tf2x32(0u, 22u, 1u, 3u, a1, b1);
  unsigned f0, f1, zf, o0_, o1_;
  unsigned jj0 = 2u * (unsigned)pt, jj1 = jj0 + 1u;
  if (jj0 < 4096u) { tf2x32(a0, a1, jj0,         jj0 + 4096u, o0_, o1_); f0 = o0_; }
  else             { tf2x32(a0, a1, jj0 - 4096u, jj0,         o0_, o1_); f0 = o1_; }
  if (jj1 < 4096u) { tf2x32(a0, a1, jj1,         jj1 + 4096u, o0_, o1_); f1 = o0_; }
  else             { tf2x32(a0, a1, jj1 - 4096u, jj1,         o0_, o1_); f1 = o1_; }
  if (pt < 2048)   { tf2x32(b0, b1, (unsigned)pt,         (unsigned)pt + 2048u, o0_, o1_); zf = o0_; }
  else             { tf2x32(b0, b1, (unsigned)pt - 2048u, (unsigned)pt,         o0_, o1_); zf = o1_; }
  xb1 = bits_to_unif(f0); xb2 = bits_to_unif(f1); zbit = zf & 1u;
}

// ---------------- jet composition, SCALED convention ----------------
// inputs q: ch0-4,23 true values; ch5-13 = true*2^-10; ch14-22 = true*2^-16.
// outputs in the same convention (scales folded into p2s/p2t/p3t).
static __device__ __forceinline__ void activate_jet(float q[NCH]) {
  const float PI1 = 3.14159265358979323846f;
  float hr = q[0] - floorf(q[0]);
  float sv = __builtin_amdgcn_sinf(hr);
  float cv = __builtin_amdgcn_cosf(hr);
  float p1 = PI1 * cv;
  float p2  = -2.0f * PI1 * PI1 * sv;
  float p3  = -4.0f * PI1 * PI1 * PI1 * cv;
  float p2s = p2 * 9.765625e-4f;        // p2 * 2^-10
  float p2t = p2 * 0.015625f;           // p2 * 2^-6  (= *2^-16 / 2^-10)
  float p3t = p3 * 1.52587890625e-5f;   // p3 * 2^-16
  float g0 = q[1], g1 = q[2], g2 = q[3], g3 = q[4];
  float s_tx = q[5], s_ty = q[6], s_tz = q[7], s_xx = q[8], s_xy = q[9],
        s_xz = q[10], s_yy = q[11], s_yz = q[12], s_zz = q[13];
  float T0 = q[14], T1 = q[15], T2 = q[16], T3 = q[17], T4 = q[18],
        T5 = q[19], T6 = q[20], T7 = q[21], T8 = q[22];
  q[0] = 0.5f * sv;
  q[1] = p1 * g0; q[2] = p1 * g1; q[3] = p1 * g2; q[4] = p1 * g3;
  q[5]  = p2s * g0 * g1 + p1 * s_tx;
  q[6]  = p2s * g0 * g2 + p1 * s_ty;
  q[7]  = p2s * g0 * g3 + p1 * s_tz;
  q[8]  = p2s * g1 * g1 + p1 * s_xx;
  q[9]  = p2s * g1 * g2 + p1 * s_xy;
  q[10] = p2s * g1 * g3 + p1 * s_xz;
  q[11] = p2s * g2 * g2 + p1 * s_yy;
  q[12] = p2s * g2 * g3 + p1 * s_yz;
  q[13] = p2s * g3 * g3 + p1 * s_zz;
  q[14] = p3t * g1 * g1 * g1 + p2t * (3.0f * s_xx * g1)              + p1 * T0;
  q[15] = p3t * g2 * g1 * g1 + p2t * (2.0f * s_xy * g1 + s_xx * g2)  + p1 * T1;
  q[16] = p3t * g3 * g1 * g1 + p2t * (2.0f * s_xz * g1 + s_xx * g3)  + p1 * T2;
  q[17] = p3t * g1 * g2 * g2 + p2t * (2.0f * s_xy * g2 + s_yy * g1)  + p1 * T3;
  q[18] = p3t * g2 * g2 * g2 + p2t * (3.0f * s_yy * g2)              + p1 * T4;
  q[19] = p3t * g3 * g2 * g2 + p2t * (2.0f * s_yz * g2 + s_yy * g3)  + p1 * T5;
  q[20] = p3t * g1 * g3 * g3 + p2t * (2.0f * s_xz * g3 + s_zz * g1)  + p1 * T6;
  q[21] = p3t * g2 * g3 * g3 + p2t * (2.0f * s_yz * g3 + s_zz * g2)  + p1 * T7;
  q[22] = p3t * g3 * g3 * g3 + p2t * (3.0f * s_zz * g3)              + p1 * T8;
  float br = q[23] - floorf(q[23]);
  q[23] = 0.5f * __builtin_amdgcn_sinf(br);
}

// k-permutation: neuron j lives at k_phys = 2*(j&63) + (j>>6)
// ---------------- prep: fp16 weight split (permuted) + RNG + out=0 --------
// wshi/wslo layout: [l][ks(4)][m(128)][quad(4)][e(8)]  (fp16 bits)
// aohi/aolo layout: [ks(4)][m(16)][quad(4)][e(8)]
__global__ __launch_bounds__(256) void prep_kernel(
    const float* __restrict__ W_hid, const float* __restrict__ W_out,
    unsigned short* __restrict__ wshi, unsigned short* __restrict__ wslo,
    unsigned short* __restrict__ aohi, unsigned short* __restrict__ aolo,
    float4* __restrict__ rnd, float* __restrict__ out) {
  int b = blockIdx.x;
  if (b == 0 && threadIdx.x == 0) out[0] = 0.0f;
  if (b < 320) {
    int idx = b * 256 + threadIdx.x;
    int l = idx >> 14, r = idx & 16383;
    int ks = r >> 12, r2 = r & 4095;
    int m = r2 >> 5, r3 = r2 & 31;
    int kp = ks * 32 + r3;
    int ko = (kp >> 1) + ((kp & 1) << 6);
    float w = W_hid[(l << 14) + (ko << 7) + m];
    unsigned short hi = f2h_bits(w);
    wshi[idx] = hi; wslo[idx] = f2h_bits(w - h2f(hi));
  } else if (b < 328) {
    int idx = (b - 320) * 256 + threadIdx.x;       // 0..2047
    int ks = idx >> 9, r2 = idx & 511;
    int m = r2 >> 5, r3 = r2 & 31;
    int kp = ks * 32 + r3;
    int ko = (kp >> 1) + ((kp & 1) << 6);
    float w = (m < 4) ? W_out[ko * 4 + m] : 0.0f;
    unsigned short hi = f2h_bits(w);
    aohi[idx] = hi; aolo[idx] = f2h_bits(w - h2f(hi));
  } else {
    int pt = (b - 328) * 256 + threadIdx.x;
    float xb1, xb2; unsigned zbit;
    bnd_rand(pt, xb1, xb2, zbit);
    rnd[pt] = make_float4(xb1, xb2, (float)zbit, zbit ? -0.5f : 0.5f);
  }
}

// ---------------- main kernel ----------------
// LDS 50688 B: B = 96 rows x 272 B fp16 (26112 B); D alias float[96][132];
// Osm at +26112 (dead D region at output stage). 4 waves: 2M x 2N grid.
__global__ __launch_bounds__(BS, 3) void pinn_kernel(
    const float* __restrict__ inputs, const float* __restrict__ y_true,
    const float* __restrict__ W_in,  const float* __restrict__ b_in,
    const float* __restrict__ b_hid, const float* __restrict__ b_out,
    const unsigned short* __restrict__ wshi,
    const unsigned short* __restrict__ wslo,
    const unsigned short* __restrict__ aohi,
    const unsigned short* __restrict__ aolo,
    const float4* __restrict__ rnd,
    float* __restrict__ out)
{
  __shared__ __align__(16) unsigned char smem[50688];
  unsigned* Bw = (unsigned*)smem;       // u32 view of fp16 jet plane
  float* Df  = (float*)smem;            // D alias
  float* Osm = (float*)(smem + OSM_OFF);

  const int t    = threadIdx.x;
  const int wave = t >> 6;
  const int lane = t & 63;
  const int quad = lane >> 4;
  const int nl   = lane & 15;
  const int wm   = wave >> 1;
  const int wn   = wave & 1;
  const int pt0  = blockIdx.x * PPB;
  const int p    = t >> 6;              // epilogue point (0..3)
  const int j0   = t & 63;              // epilogue neuron pair (j0, j0+64)
  const int pt   = pt0 + p;

  // ---- layer 1 (4 -> 128), fp32 scalar, thread (p, j0) & (p, j0+64)
  {
    float4 rv = rnd[pt];
    float x_t = inputs[pt * 4 + 0], x_x = inputs[pt * 4 + 1];
    float x_y = inputs[pt * 4 + 2], x_z = inputs[pt * 4 + 3];
    float q0[NCH], q1[NCH];
#pragma unroll
    for (int h = 0; h < 2; ++h) {
      int jj = j0 + h * 64;
      float* q = h ? q1 : q0;
      float w0 = W_in[0 * DD + jj], w1 = W_in[1 * DD + jj],
            w2 = W_in[2 * DD + jj], w3 = W_in[3 * DD + jj];
      float bb = b_in[jj];
      q[0] = bb + x_t * w0 + x_x * w1 + x_y * w2 + x_z * w3;
      q[1] = w0; q[2] = w1; q[3] = w2; q[4] = w3;
#pragma unroll
      for (int c = 5; c < 23; ++c) q[c] = 0.0f;
      q[23] = bb + x_t * w0 + rv.x * w1 + rv.y * w2 + rv.z * w3;
      activate_jet(q);
    }
#pragma unroll
    for (int c = 0; c < NCH; ++c)
      Bw[(p * NCH + c) * RSW + j0] = pk2(q0[c], q1[c]);
  }

  // ---- hidden layers: GEMM M=128 x N=96 x K=128, fp16 W-split 2-MFMA
  for (int l = 0; l < NHID; ++l) {
    __syncthreads();   // (1) B ready
    f32x4 acc[4][3];
#pragma unroll
    for (int mt = 0; mt < 4; ++mt)
#pragma unroll
      for (int nt = 0; nt < 3; ++nt) acc[mt][nt] = (f32x4)0.0f;

    const half8* pB   = (const half8*)smem;
    const half8* pAhi = ((const half8*)wshi) + (l << 11);
    const half8* pAlo = ((const half8*)wslo) + (l << 11);

#pragma unroll
    for (int ks = 0; ks < 4; ++ks) {
      half8 bh[3], ah[4], al[4];
#pragma unroll
      for (int nt = 0; nt < 3; ++nt)
        bh[nt] = pB[(wn * 48 + nt * 16 + nl) * RS8 + ks * 4 + quad];
#pragma unroll
      for (int mt = 0; mt < 4; ++mt) {
        int m = wm * 64 + mt * 16 + nl;
        ah[mt] = pAhi[ks * 512 + m * 4 + quad];
        al[mt] = pAlo[ks * 512 + m * 4 + quad];
      }
#pragma unroll
      for (int mt = 0; mt < 4; ++mt)
#pragma unroll
        for (int nt = 0; nt < 3; ++nt) {
          acc[mt][nt] = __builtin_amdgcn_mfma_f32_16x16x32_f16(ah[mt], bh[nt], acc[mt][nt], 0, 0, 0);
          acc[mt][nt] = __builtin_amdgcn_mfma_f32_16x16x32_f16(al[mt], bh[nt], acc[mt][nt], 0, 0, 0);
        }
    }
    __syncthreads();   // (2) B reads done; D may overwrite

#pragma unroll
    for (int mt = 0; mt < 4; ++mt)
#pragma unroll
      for (int nt = 0; nt < 3; ++nt) {
        int n  = wn * 48 + nt * 16 + nl;
        int mb = wm * 64 + mt * 16 + (quad << 2);
        *(f32x4*)(Df + n * DST + mb) = acc[mt][nt];
      }
    __syncthreads();   // (3) D complete

    float q0[NCH], q1[NCH];
#pragma unroll
    for (int c = 0; c < NCH; ++c) {
      q0[c] = Df[(p * NCH + c) * DST + j0];
      q1[c] = Df[(p * NCH + c) * DST + j0 + 64];
    }
    __syncthreads();   // (4) D reads done; B may overwrite

    float b0 = b_hid[l * DD + j0];
    float b1 = b_hid[l * DD + j0 + 64];
    q0[0] += b0; q0[23] += b0;
    q1[0] += b1; q1[23] += b1;
    activate_jet(q0);
    activate_jet(q1);
#pragma unroll
    for (int c = 0; c < NCH; ++c)
      Bw[(p * NCH + c) * RSW + j0] = pk2(q0[c], q1[c]);
  }
  __syncthreads();     // final jets ready

  // ---- output layer: padded M=16 GEMM; wave w handles tiles {w, w+4|w<2}
  {
    const int ntl = (wave < 2) ? 2 : 1;
    f32x4 acc2[2];
    acc2[0] = (f32x4)0.0f; acc2[1] = (f32x4)0.0f;
    const half8* pB  = (const half8*)smem;
    const half8* pAh = (const half8*)aohi;
    const half8* pAl = (const half8*)aolo;
#pragma unroll
    for (int ks = 0; ks < 4; ++ks) {
      half8 ah = pAh[ks * 64 + nl * 4 + quad];
      half8 al = pAl[ks * 64 + nl * 4 + quad];
      for (int i = 0; i < ntl; ++i) {
        int nt = wave + i * 4;
        half8 bh = pB[(nt * 16 + nl) * RS8 + ks * 4 + quad];
        acc2[i] = __builtin_amdgcn_mfma_f32_16x16x32_f16(ah, bh, acc2[i], 0, 0, 0);
        acc2[i] = __builtin_amdgcn_mfma_f32_16x16x32_f16(al, bh, acc2[i], 0, 0, 0);
      }
    }
    if (quad == 0) {      // rows m=0..3 are the 4 real outputs
      for (int i = 0; i < ntl; ++i) {
        int n = (wave + i * 4) * 16 + nl;
        *(f32x4*)(Osm + n * 4) = acc2[i];   // Osm region dead since barrier
      }
    }
  }
  __syncthreads();     // O ready

  // ---- loss epilogue: threads 0..3 (one point each)
  if (t < PPB) {
    const int pp = t;
    const int ptt = pt0 + pp;
    const float Ttrue = rnd[ptt].w;
    const float SEC  = SS_INV;                              // 2nd-deriv unscale
    const float SCT  = 8.36660026534e-04f * ST_INV;         // sqrt(Pr/Ra)*2^16
    const float KAPS = 1.19522860933e-03f * SS_INV;         // kappa*2^10
    float bo0 = b_out[0], bo1 = b_out[1], bo2 = b_out[2], bo3 = b_out[3];
#define OO(o, c) Osm[(pp * NCH + (c)) * 4 + (o)]
    float u  = OO(0, 0) + bo0, v_ = OO(1, 0) + bo1, w_ = OO(2, 0) + bo2;
    float ux = OO(0, 2), uy = OO(0, 3), uz = OO(0, 4);
    float vx = OO(1, 2), vy = OO(1, 3), vz = OO(1, 4);
    float wx = OO(2, 2), wy = OO(2, 3), wz = OO(2, 4);
    float Tt = OO(3, 1), Tx = OO(3, 2), Ty = OO(3, 3), Tz = OO(3, 4);

    float hu = OO(2, 6) - OO(1, 7)
             + u  * (OO(2, 9)  - OO(1, 10))
             + v_ * (OO(2, 11) - OO(1, 12))
             + w_ * (OO(2, 12) - OO(1, 13));
    float NSEu = SEC * hu
               - (wy - vz) * ux - (uz - wx) * uy - (vx - uy) * uz
               - SCT * (OO(2, 15) - OO(1, 16) + OO(2, 18) - OO(1, 19) + OO(2, 21) - OO(1, 22))
               - Ty;
    float hv = OO(0, 7) - OO(2, 5)
             + u  * (OO(0, 10) - OO(2, 8))
             + v_ * (OO(0, 12) - OO(2, 9))
             + w_ * (OO(0, 13) - OO(2, 10));
    float NSEv = SEC * hv
               - (wy - vz) * vx - (uz - wx) * vy - (vx - uy) * vz
               - SCT * (OO(0, 16) - OO(2, 14) + OO(0, 19) - OO(2, 17) + OO(0, 22) - OO(2, 20))
               + Tx;
    float hw = OO(1, 5) - OO(0, 6)
             + u  * (OO(1, 8)  - OO(0, 9))
             + v_ * (OO(1, 9)  - OO(0, 11))
             + w_ * (OO(1, 10) - OO(0, 12));
    float NSEw = SEC * hw
               - (wy - vz) * wx - (uz - wx) * wy - (vx - uy) * wz
               - SCT * (OO(1, 14) - OO(0, 15) + OO(1, 17) - OO(0, 18) + OO(1, 20) - OO(0, 21));

    float EE = Tt + u * Tx + v_ * Ty + w_ * Tz
             - KAPS * (OO(3, 8) + OO(3, 11) + OO(3, 13));

    float conti = ux + vy + wz;
    const float* yt = y_true + ptt * 4;
    float d0 = u - yt[0], d1 = v_ - yt[1], d2 = w_ - yt[2];
    float dT = Ttrue - (OO(3, 23) + bo3);
#undef OO
    const float invN  = 1.0f / (float)NPTS;
    const float inv3N = 1.0f / (3.0f * (float)NPTS);
    float part = (d0 * d0 + d1 * d1 + d2 * d2) * inv3N
               + conti * conti * invN
               + (NSEu * NSEu + NSEv * NSEv + NSEw * NSEw) * inv3N
               + EE * EE * invN
               + dT * dT * invN;
    atomicAdd(out, part);
  }
}

extern "C" void kernel_launch(void* const* d_in, const int* in_sizes, int n_in,
                              void* d_out, int out_size, void* d_ws, size_t ws_size,
                              hipStream_t stream) {
  const float* inputs = (const float*)d_in[0];
  const float* y_true = (const float*)d_in[1];
  const float* W_in   = (const float*)d_in[2];
  const float* b_in   = (const float*)d_in[3];
  const float* W_hid  = (const float*)d_in[4];
  const float* b_hid  = (const float*)d_in[5];
  const float* W_out  = (const float*)d_in[6];
  const float* b_out  = (const float*)d_in[7];
  float* out = (float*)d_out;

  unsigned char* ws = (unsigned char*)d_ws;
  unsigned short* wshi = (unsigned short*)(ws);            // 163840 B
  unsigned short* wslo = (unsigned short*)(ws + 163840);   // 163840 B
  unsigned short* aohi = (unsigned short*)(ws + 327680);   // 4096 B
  unsigned short* aolo = (unsigned short*)(ws + 331776);   // 4096 B
  float4*         rnd  = (float4*)(ws + 335872);           // 65536 B

  prep_kernel<<<344, 256, 0, stream>>>(W_hid, W_out, wshi, wslo, aohi, aolo,
                                       rnd, out);
  pinn_kernel<<<NPTS / PPB, BS, 0, stream>>>(inputs, y_true, W_in, b_in,
                                             b_hid, b_out,
                                             wshi, wslo, aohi, aolo, rnd, out);
}

// Round 9
// 116.126 us; speedup vs baseline: 2.9136x; 1.1894x over previous
//
#include <hip/hip_runtime.h>
#include <math.h>

#define NPTS 4096
#define DD   128
#define NCH  24
#define NHID 5
#define PPB  4            // points per block (= quad)
#define BS   256
#define WP8  17           // jet plane row stride in half8 units (136 fp16)
#define WPW  68           // jet plane row stride in u32 units
#define PLSZ 26112        // one jet plane: 96 rows x 272 B
#define OSM_OFF 52224     // Osm after the two planes
// jet row for (point p, channel c)
#define ROWM(p,c) (16*((c)>>2) + 4*(p) + ((c)&3))

typedef __attribute__((ext_vector_type(8))) _Float16 half8;
typedef __attribute__((ext_vector_type(4))) float f32x4;

// channel scales: ch0-4,23: 1; ch5-13 (2nd): 2^-10; ch14-22 (3rd): 2^-16
#define SS_INV 1024.0f
#define ST_INV 65536.0f

static __device__ __forceinline__ unsigned short f2h_bits(float x) {
  _Float16 h = (_Float16)x; unsigned short u; __builtin_memcpy(&u, &h, 2); return u;
}
static __device__ __forceinline__ float h2f(unsigned short u) {
  _Float16 h; __builtin_memcpy(&h, &u, 2); return (float)h;
}
static __device__ __forceinline__ unsigned pk2(float a, float b) {
  return (unsigned)f2h_bits(a) | ((unsigned)f2h_bits(b) << 16);
}

// ---------------- threefry2x32 (matches JAX's PRNG) ----------------
static __device__ __forceinline__ void tf2x32(unsigned k0, unsigned k1,
                                              unsigned x0, unsigned x1,
                                              unsigned &o0, unsigned &o1) {
  unsigned ks2 = 0x1BD11BDAu ^ k0 ^ k1;
  x0 += k0; x1 += k1;
#define TFR(r) { x0 += x1; x1 = (x1 << (r)) | (x1 >> (32 - (r))); x1 ^= x0; }
  TFR(13) TFR(15) TFR(26) TFR(6)  x0 += k1;  x1 += ks2 + 1u;
  TFR(17) TFR(29) TFR(16) TFR(24) x0 += ks2; x1 += k0 + 2u;
  TFR(13) TFR(15) TFR(26) TFR(6)  x0 += k0;  x1 += k1 + 3u;
  TFR(17) TFR(29) TFR(16) TFR(24) x0 += k1;  x1 += ks2 + 4u;
  TFR(13) TFR(15) TFR(26) TFR(6)  x0 += ks2; x1 += k0 + 5u;
#undef TFR
  o0 = x0; o1 = x1;
}
static __device__ __forceinline__ float bits_to_unif(unsigned b) {
  return __uint_as_float((b >> 9) | 0x3f800000u) - 1.0f;
}
static __device__ __forceinline__ void bnd_rand(int pt, float &xb1, float &xb2,
                                                unsigned &zbit) {
  unsigned a0, a1, b0, b1;
  tf2x32(0u, 22u, 0u, 2u, a0, b0);
  tf2x32(0u, 22u, 1u, 3u, a1, b1);
  unsigned f0, f1, zf, o0_, o1_;
  unsigned jj0 = 2u * (unsigned)pt, jj1 = jj0 + 1u;
  if (jj0 < 4096u) { tf2x32(a0, a1, jj0,         jj0 + 4096u, o0_, o1_); f0 = o0_; }
  else             { tf2x32(a0, a1, jj0 - 4096u, jj0,         o0_, o1_); f0 = o1_; }
  if (jj1 < 4096u) { tf2x32(a0, a1, jj1,         jj1 + 4096u, o0_, o1_); f1 = o0_; }
  else             { tf2x32(a0, a1, jj1 - 4096u, jj1,         o0_, o1_); f1 = o1_; }
  if (pt < 2048)   { tf2x32(b0, b1, (unsigned)pt,         (unsigned)pt + 2048u, o0_, o1_); zf = o0_; }
  else             { tf2x32(b0, b1, (unsigned)pt - 2048u, (unsigned)pt,         o0_, o1_); zf = o1_; }
  xb1 = bits_to_unif(f0); xb2 = bits_to_unif(f1); zbit = zf & 1u;
}

// ---------------- jet composition, SCALED convention ----------------
static __device__ __forceinline__ void activate_jet(float q[NCH]) {
  const float PI1 = 3.14159265358979323846f;
  float hr = q[0] - floorf(q[0]);
  float sv = __builtin_amdgcn_sinf(hr);
  float cv = __builtin_amdgcn_cosf(hr);
  float p1 = PI1 * cv;
  float p2  = -2.0f * PI1 * PI1 * sv;
  float p3  = -4.0f * PI1 * PI1 * PI1 * cv;
  float p2s = p2 * 9.765625e-4f;        // p2 * 2^-10
  float p2t = p2 * 0.015625f;           // p2 * 2^-6
  float p3t = p3 * 1.52587890625e-5f;   // p3 * 2^-16
  float g0 = q[1], g1 = q[2], g2 = q[3], g3 = q[4];
  float s_tx = q[5], s_ty = q[6], s_tz = q[7], s_xx = q[8], s_xy = q[9],
        s_xz = q[10], s_yy = q[11], s_yz = q[12], s_zz = q[13];
  float T0 = q[14], T1 = q[15], T2 = q[16], T3 = q[17], T4 = q[18],
        T5 = q[19], T6 = q[20], T7 = q[21], T8 = q[22];
  q[0] = 0.5f * sv;
  q[1] = p1 * g0; q[2] = p1 * g1; q[3] = p1 * g2; q[4] = p1 * g3;
  q[5]  = p2s * g0 * g1 + p1 * s_tx;
  q[6]  = p2s * g0 * g2 + p1 * s_ty;
  q[7]  = p2s * g0 * g3 + p1 * s_tz;
  q[8]  = p2s * g1 * g1 + p1 * s_xx;
  q[9]  = p2s * g1 * g2 + p1 * s_xy;
  q[10] = p2s * g1 * g3 + p1 * s_xz;
  q[11] = p2s * g2 * g2 + p1 * s_yy;
  q[12] = p2s * g2 * g3 + p1 * s_yz;
  q[13] = p2s * g3 * g3 + p1 * s_zz;
  q[14] = p3t * g1 * g1 * g1 + p2t * (3.0f * s_xx * g1)              + p1 * T0;
  q[15] = p3t * g2 * g1 * g1 + p2t * (2.0f * s_xy * g1 + s_xx * g2)  + p1 * T1;
  q[16] = p3t * g3 * g1 * g1 + p2t * (2.0f * s_xz * g1 + s_xx * g3)  + p1 * T2;
  q[17] = p3t * g1 * g2 * g2 + p2t * (2.0f * s_xy * g2 + s_yy * g1)  + p1 * T3;
  q[18] = p3t * g2 * g2 * g2 + p2t * (3.0f * s_yy * g2)              + p1 * T4;
  q[19] = p3t * g3 * g2 * g2 + p2t * (2.0f * s_yz * g2 + s_yy * g3)  + p1 * T5;
  q[20] = p3t * g1 * g3 * g3 + p2t * (2.0f * s_xz * g3 + s_zz * g1)  + p1 * T6;
  q[21] = p3t * g2 * g3 * g3 + p2t * (2.0f * s_yz * g3 + s_zz * g2)  + p1 * T7;
  q[22] = p3t * g3 * g3 * g3 + p2t * (3.0f * s_zz * g3)              + p1 * T8;
  float br = q[23] - floorf(q[23]);
  q[23] = 0.5f * __builtin_amdgcn_sinf(br);
}

// k-slot permutation: neuron j sits at slot s = 32*(j>>5) + 2*(j&15) + ((j>>4)&1)
// inverse: j(s) = 32*(s>>5) + 16*(s&1) + ((s>>1)&15)
// With s = ks*32 + quad*8 + e:  j = 32*ks + 16*(e&1) + 4*quad + (e>>1)
// ---------------- prep: weights as B-operand (fp16 hi/lo) + RNG + out=0 ---
// wshi/wslo: [l][nt(8)][ks(4)][nl(16)][quad(4)][e(8)]  (fp16 bits)
// aohi/aolo: [ks(4)][nl(16)][quad(4)][e(8)]
__global__ __launch_bounds__(256) void prep_kernel(
    const float* __restrict__ W_hid, const float* __restrict__ W_out,
    unsigned short* __restrict__ wshi, unsigned short* __restrict__ wslo,
    unsigned short* __restrict__ aohi, unsigned short* __restrict__ aolo,
    float4* __restrict__ rnd, float* __restrict__ out) {
  int b = blockIdx.x;
  if (b == 0 && threadIdx.x == 0) out[0] = 0.0f;
  if (b < 320) {
    int idx = b * 256 + threadIdx.x;          // [l][nt][ks][nl][quad][e]
    int l = idx >> 14, r = idx & 16383;
    int nt = r >> 11, r2 = r & 2047;
    int ks = r2 >> 9, r3 = r2 & 511;
    int nl = r3 >> 5, r4 = r3 & 31;
    int quad = r4 >> 3, e = r4 & 7;
    int jin  = 32 * ks + 16 * (e & 1) + 4 * quad + (e >> 1);
    int jout = nt * 16 + nl;
    float w = W_hid[(l << 14) + (jin << 7) + jout];
    unsigned short hi = f2h_bits(w);
    wshi[idx] = hi; wslo[idx] = f2h_bits(w - h2f(hi));
  } else if (b < 328) {
    int idx = (b - 320) * 256 + threadIdx.x;  // 0..2047: [ks][nl][quad][e]
    int ks = idx >> 9, r3 = idx & 511;
    int nl = r3 >> 5, r4 = r3 & 31;
    int quad = r4 >> 3, e = r4 & 7;
    int jin = 32 * ks + 16 * (e & 1) + 4 * quad + (e >> 1);
    float w = (nl < 4) ? W_out[jin * 4 + nl] : 0.0f;
    unsigned short hi = f2h_bits(w);
    aohi[idx] = hi; aolo[idx] = f2h_bits(w - h2f(hi));
  } else {
    int pt = (b - 328) * 256 + threadIdx.x;
    float xb1, xb2; unsigned zbit;
    bnd_rand(pt, xb1, xb2, zbit);
    rnd[pt] = make_float4(xb1, xb2, (float)zbit, zbit ? -0.5f : 0.5f);
  }
}

// ---------------- main kernel ----------------
// LDS 53760 B: two jet planes (A-operand layout, 96 rows x 136 fp16) +
// Osm (4 pts x 24 ch x 4 outs f32). Flipped GEMM: A=jets(M=96), B=W(N=128).
// One barrier per layer; activation fully in-register.
__global__ __launch_bounds__(BS, 3) void pinn_kernel(
    const float* __restrict__ inputs, const float* __restrict__ y_true,
    const float* __restrict__ W_in,  const float* __restrict__ b_in,
    const float* __restrict__ b_hid, const float* __restrict__ b_out,
    const unsigned short* __restrict__ wshi,
    const unsigned short* __restrict__ wslo,
    const unsigned short* __restrict__ aohi,
    const unsigned short* __restrict__ aolo,
    const float4* __restrict__ rnd,
    float* __restrict__ out)
{
  __shared__ __align__(16) unsigned char smem[53760];
  _Float16* plane0 = (_Float16*)smem;
  _Float16* plane1 = (_Float16*)(smem + PLSZ);
  float* Osm = (float*)(smem + OSM_OFF);

  const int t    = threadIdx.x;
  const int wave = t >> 6;
  const int lane = t & 63;
  const int q    = lane >> 4;          // quad = point p in C-layout
  const int nl   = lane & 15;
  const int P    = 16 * wave + nl;     // k-slot pair id for jet writes
  const int ja   = 32 * wave + nl;     // neuron of n-tile 2*wave
  const int jb   = ja + 16;            // neuron of n-tile 2*wave+1
  const int pt0  = blockIdx.x * PPB;

  // ---- layer 1 (4 -> 128): thread (p1 = wave, P1 = lane) -> neurons j1a,j1b
  {
    const int p1 = t >> 6;
    const int P1 = lane;
    const int j1a = 32 * (P1 >> 4) + (P1 & 15), j1b = j1a + 16;
    const int pt = pt0 + p1;
    float4 rv = rnd[pt];
    float x_t = inputs[pt * 4 + 0], x_x = inputs[pt * 4 + 1];
    float x_y = inputs[pt * 4 + 2], x_z = inputs[pt * 4 + 3];
    float q0[NCH], q1[NCH];
#pragma unroll
    for (int h = 0; h < 2; ++h) {
      int jj = h ? j1b : j1a;
      float* qq = h ? q1 : q0;
      float w0 = W_in[0 * DD + jj], w1 = W_in[1 * DD + jj],
            w2 = W_in[2 * DD + jj], w3 = W_in[3 * DD + jj];
      float bb = b_in[jj];
      qq[0] = bb + x_t * w0 + x_x * w1 + x_y * w2 + x_z * w3;
      qq[1] = w0; qq[2] = w1; qq[3] = w2; qq[4] = w3;
#pragma unroll
      for (int c = 5; c < 23; ++c) qq[c] = 0.0f;
      qq[23] = bb + x_t * w0 + rv.x * w1 + rv.y * w2 + rv.z * w3;
      activate_jet(qq);
    }
    unsigned* dw = (unsigned*)plane0;
#pragma unroll
    for (int c = 0; c < NCH; ++c)
      dw[ROWM(p1, c) * WPW + P1] = pk2(q0[c], q1[c]);
  }
  __syncthreads();

  // ---- hidden layers: flipped GEMM M=96(jets) x N=128(neurons) x K=128
  const half8* wh8 = (const half8*)wshi;
  const half8* wl8 = (const half8*)wslo;
  for (int l = 0; l < NHID; ++l) {
    const half8* src = (const half8*)((l & 1) ? plane1 : plane0);
    unsigned* dstw = (unsigned*)((l & 1) ? plane0 : plane1);

    f32x4 acc[6][2];
#pragma unroll
    for (int mt = 0; mt < 6; ++mt) { acc[mt][0] = (f32x4)0.0f; acc[mt][1] = (f32x4)0.0f; }

#pragma unroll
    for (int ks = 0; ks < 4; ++ks) {
      half8 a[6], bh[2], bl[2];
#pragma unroll
      for (int mt = 0; mt < 6; ++mt)
        a[mt] = src[(16 * mt + nl) * WP8 + ks * 4 + q];
#pragma unroll
      for (int i = 0; i < 2; ++i) {
        int bi = ((l * 8 + 2 * wave + i) * 4 + ks) * 64 + nl * 4 + q;
        bh[i] = wh8[bi]; bl[i] = wl8[bi];
      }
#pragma unroll
      for (int mt = 0; mt < 6; ++mt)
#pragma unroll
        for (int i = 0; i < 2; ++i) {
          acc[mt][i] = __builtin_amdgcn_mfma_f32_16x16x32_f16(a[mt], bh[i], acc[mt][i], 0, 0, 0);
          acc[mt][i] = __builtin_amdgcn_mfma_f32_16x16x32_f16(a[mt], bl[i], acc[mt][i], 0, 0, 0);
        }
    }

    // in-register activation: lane holds all 24 channels of point q for ja, jb
    float qa[NCH], qb[NCH];
#pragma unroll
    for (int mt = 0; mt < 6; ++mt)
#pragma unroll
      for (int r = 0; r < 4; ++r) {
        qa[4 * mt + r] = acc[mt][0][r];
        qb[4 * mt + r] = acc[mt][1][r];
      }
    float ba = b_hid[l * DD + ja], bb_ = b_hid[l * DD + jb];
    qa[0] += ba; qa[23] += ba;
    qb[0] += bb_; qb[23] += bb_;
    activate_jet(qa);
    activate_jet(qb);
#pragma unroll
    for (int c = 0; c < NCH; ++c)
      dstw[ROWM(q, c) * WPW + P] = pk2(qa[c], qb[c]);
    __syncthreads();   // dst plane complete; src plane reads all done
  }

  // ---- output layer: A = final jets (plane1), B = W_out padded (N=16)
  // wave w<3 handles m-tiles {2w, 2w+1}; lane (q, nl<4) -> point q, output nl
  {
    const half8* src = (const half8*)plane1;   // NHID odd -> final in plane1
    const half8* oh8 = (const half8*)aohi;
    const half8* ol8 = (const half8*)aolo;
    if (wave < 3) {
      f32x4 acc2[2];
      acc2[0] = (f32x4)0.0f; acc2[1] = (f32x4)0.0f;
#pragma unroll
      for (int ks = 0; ks < 4; ++ks) {
        half8 a0 = src[(16 * (2 * wave)     + nl) * WP8 + ks * 4 + q];
        half8 a1 = src[(16 * (2 * wave + 1) + nl) * WP8 + ks * 4 + q];
        int bi = ks * 64 + nl * 4 + q;
        half8 oh = oh8[bi], ol = ol8[bi];
        acc2[0] = __builtin_amdgcn_mfma_f32_16x16x32_f16(a0, oh, acc2[0], 0, 0, 0);
        acc2[0] = __builtin_amdgcn_mfma_f32_16x16x32_f16(a0, ol, acc2[0], 0, 0, 0);
        acc2[1] = __builtin_amdgcn_mfma_f32_16x16x32_f16(a1, oh, acc2[1], 0, 0, 0);
        acc2[1] = __builtin_amdgcn_mfma_f32_16x16x32_f16(a1, ol, acc2[1], 0, 0, 0);
      }
      if (nl < 4) {
#pragma unroll
        for (int i = 0; i < 2; ++i)
#pragma unroll
          for (int r = 0; r < 4; ++r)
            Osm[(q * NCH + 4 * (2 * wave + i) + r) * 4 + nl] = acc2[i][r];
      }
    }
  }
  __syncthreads();     // Osm ready

  // ---- loss epilogue: threads 0..3 (one point each)
  if (t < PPB) {
    const int pp = t;
    const int ptt = pt0 + pp;
    const float Ttrue = rnd[ptt].w;
    const float SEC  = SS_INV;                              // 2nd-deriv unscale
    const float SCT  = 8.36660026534e-04f * ST_INV;         // sqrt(Pr/Ra)*2^16
    const float KAPS = 1.19522860933e-03f * SS_INV;         // kappa*2^10
    float bo0 = b_out[0], bo1 = b_out[1], bo2 = b_out[2], bo3 = b_out[3];
#define OO(o, c) Osm[(pp * NCH + (c)) * 4 + (o)]
    float u  = OO(0, 0) + bo0, v_ = OO(1, 0) + bo1, w_ = OO(2, 0) + bo2;
    float ux = OO(0, 2), uy = OO(0, 3), uz = OO(0, 4);
    float vx = OO(1, 2), vy = OO(1, 3), vz = OO(1, 4);
    float wx = OO(2, 2), wy = OO(2, 3), wz = OO(2, 4);
    float Tt = OO(3, 1), Tx = OO(3, 2), Ty = OO(3, 3), Tz = OO(3, 4);

    float hu = OO(2, 6) - OO(1, 7)
             + u  * (OO(2, 9)  - OO(1, 10))
             + v_ * (OO(2, 11) - OO(1, 12))
             + w_ * (OO(2, 12) - OO(1, 13));
    float NSEu = SEC * hu
               - (wy - vz) * ux - (uz - wx) * uy - (vx - uy) * uz
               - SCT * (OO(2, 15) - OO(1, 16) + OO(2, 18) - OO(1, 19) + OO(2, 21) - OO(1, 22))
               - Ty;
    float hv = OO(0, 7) - OO(2, 5)
             + u  * (OO(0, 10) - OO(2, 8))
             + v_ * (OO(0, 12) - OO(2, 9))
             + w_ * (OO(0, 13) - OO(2, 10));
    float NSEv = SEC * hv
               - (wy - vz) * vx - (uz - wx) * vy - (vx - uy) * vz
               - SCT * (OO(0, 16) - OO(2, 14) + OO(0, 19) - OO(2, 17) + OO(0, 22) - OO(2, 20))
               + Tx;
    float hw = OO(1, 5) - OO(0, 6)
             + u  * (OO(1, 8)  - OO(0, 9))
             + v_ * (OO(1, 9)  - OO(0, 11))
             + w_ * (OO(1, 10) - OO(0, 12));
    float NSEw = SEC * hw
               - (wy - vz) * wx - (uz - wx) * wy - (vx - uy) * wz
               - SCT * (OO(1, 14) - OO(0, 15) + OO(1, 17) - OO(0, 18) + OO(1, 20) - OO(0, 21));

    float EE = Tt + u * Tx + v_ * Ty + w_ * Tz
             - KAPS * (OO(3, 8) + OO(3, 11) + OO(3, 13));

    float conti = ux + vy + wz;
    const float* yt = y_true + ptt * 4;
    float d0 = u - yt[0], d1 = v_ - yt[1], d2 = w_ - yt[2];
    float dT = Ttrue - (OO(3, 23) + bo3);
#undef OO
    const float invN  = 1.0f / (float)NPTS;
    const float inv3N = 1.0f / (3.0f * (float)NPTS);
    float part = (d0 * d0 + d1 * d1 + d2 * d2) * inv3N
               + conti * conti * invN
               + (NSEu * NSEu + NSEv * NSEv + NSEw * NSEw) * inv3N
               + EE * EE * invN
               + dT * dT * invN;
    atomicAdd(out, part);
  }
}

extern "C" void kernel_launch(void* const* d_in, const int* in_sizes, int n_in,
                              void* d_out, int out_size, void* d_ws, size_t ws_size,
                              hipStream_t stream) {
  const float* inputs = (const float*)d_in[0];
  const float* y_true = (const float*)d_in[1];
  const float* W_in   = (const float*)d_in[2];
  const float* b_in   = (const float*)d_in[3];
  const float* W_hid  = (const float*)d_in[4];
  const float* b_hid  = (const float*)d_in[5];
  const float* W_out  = (const float*)d_in[6];
  const float* b_out  = (const float*)d_in[7];
  float* out = (float*)d_out;

  unsigned char* ws = (unsigned char*)d_ws;
  unsigned short* wshi = (unsigned short*)(ws);            // 163840 B
  unsigned short* wslo = (unsigned short*)(ws + 163840);   // 163840 B
  unsigned short* aohi = (unsigned short*)(ws + 327680);   // 4096 B
  unsigned short* aolo = (unsigned short*)(ws + 331776);   // 4096 B
  float4*         rnd  = (float4*)(ws + 335872);           // 65536 B

  prep_kernel<<<344, 256, 0, stream>>>(W_hid, W_out, wshi, wslo, aohi, aolo,
                                       rnd, out);
  pinn_kernel<<<NPTS / PPB, BS, 0, stream>>>(inputs, y_true, W_in, b_in,
                                             b_hid, b_out,
                                             wshi, wslo, aohi, aolo, rnd, out);
}

// Round 10
// 95.259 us; speedup vs baseline: 3.5518x; 1.2191x over previous
//
#include <hip/hip_runtime.h>
#include <math.h>

#define NPTS 4096
#define DD   128
#define NCH  24
#define NHID 5
#define PPB  4            // points per block (= quad)
#define BS   256
#define WP8  17           // jet plane row stride in half8 units (136 fp16)
#define WPW  68           // jet plane row stride in u32 units
#define PLSZ 26112        // one jet plane: 96 rows x 272 B
#define OSM_OFF 52224     // Osm after the two planes
// jet row for (point p, channel c)
#define ROWM(p,c) (16*((c)>>2) + 4*(p) + ((c)&3))

typedef __attribute__((ext_vector_type(8))) _Float16 half8;
typedef __attribute__((ext_vector_type(2))) __fp16 fp16x2;
typedef __attribute__((ext_vector_type(4))) float f32x4;

// channel scales: ch0-4,23: 1; ch5-13 (2nd): 2^-10; ch14-22 (3rd): 2^-16
#define SS_INV 1024.0f
#define ST_INV 65536.0f

static __device__ __forceinline__ unsigned short f2h_bits(float x) {
  _Float16 h = (_Float16)x; unsigned short u; __builtin_memcpy(&u, &h, 2); return u;
}
static __device__ __forceinline__ unsigned pk2(float a, float b) {
  fp16x2 h = __builtin_amdgcn_cvt_pkrtz(a, b);   // 1 inst, packs 2 fp16 (RTZ)
  unsigned u; __builtin_memcpy(&u, &h, 4); return u;
}

// ---------------- threefry2x32 (matches JAX's PRNG) ----------------
static __device__ __forceinline__ void tf2x32(unsigned k0, unsigned k1,
                                              unsigned x0, unsigned x1,
                                              unsigned &o0, unsigned &o1) {
  unsigned ks2 = 0x1BD11BDAu ^ k0 ^ k1;
  x0 += k0; x1 += k1;
#define TFR(r) { x0 += x1; x1 = (x1 << (r)) | (x1 >> (32 - (r))); x1 ^= x0; }
  TFR(13) TFR(15) TFR(26) TFR(6)  x0 += k1;  x1 += ks2 + 1u;
  TFR(17) TFR(29) TFR(16) TFR(24) x0 += ks2; x1 += k0 + 2u;
  TFR(13) TFR(15) TFR(26) TFR(6)  x0 += k0;  x1 += k1 + 3u;
  TFR(17) TFR(29) TFR(16) TFR(24) x0 += k1;  x1 += ks2 + 4u;
  TFR(13) TFR(15) TFR(26) TFR(6)  x0 += ks2; x1 += k0 + 5u;
#undef TFR
  o0 = x0; o1 = x1;
}
static __device__ __forceinline__ float bits_to_unif(unsigned b) {
  return __uint_as_float((b >> 9) | 0x3f800000u) - 1.0f;
}
static __device__ __forceinline__ void bnd_rand(int pt, float &xb1, float &xb2,
                                                unsigned &zbit) {
  unsigned a0, a1, b0, b1;
  tf2x32(0u, 22u, 0u, 2u, a0, b0);
  tf2x32(0u, 22u, 1u, 3u, a1, b1);
  unsigned f0, f1, zf, o0_, o1_;
  unsigned jj0 = 2u * (unsigned)pt, jj1 = jj0 + 1u;
  if (jj0 < 4096u) { tf2x32(a0, a1, jj0,         jj0 + 4096u, o0_, o1_); f0 = o0_; }
  else             { tf2x32(a0, a1, jj0 - 4096u, jj0,         o0_, o1_); f0 = o1_; }
  if (jj1 < 4096u) { tf2x32(a0, a1, jj1,         jj1 + 4096u, o0_, o1_); f1 = o0_; }
  else             { tf2x32(a0, a1, jj1 - 4096u, jj1,         o0_, o1_); f1 = o1_; }
  if (pt < 2048)   { tf2x32(b0, b1, (unsigned)pt,         (unsigned)pt + 2048u, o0_, o1_); zf = o0_; }
  else             { tf2x32(b0, b1, (unsigned)pt - 2048u, (unsigned)pt,         o0_, o1_); zf = o1_; }
  xb1 = bits_to_unif(f0); xb2 = bits_to_unif(f1); zbit = zf & 1u;
}

// ---------------- jet composition, SCALED convention ----------------
static __device__ __forceinline__ void activate_jet(float q[NCH]) {
  const float PI1 = 3.14159265358979323846f;
  float hr = q[0] - floorf(q[0]);
  float sv = __builtin_amdgcn_sinf(hr);
  float cv = __builtin_amdgcn_cosf(hr);
  float p1 = PI1 * cv;
  float p2  = -2.0f * PI1 * PI1 * sv;
  float p3  = -4.0f * PI1 * PI1 * PI1 * cv;
  float p2s = p2 * 9.765625e-4f;        // p2 * 2^-10
  float p2t = p2 * 0.015625f;           // p2 * 2^-6
  float p3t = p3 * 1.52587890625e-5f;   // p3 * 2^-16
  float g0 = q[1], g1 = q[2], g2 = q[3], g3 = q[4];
  float s_tx = q[5], s_ty = q[6], s_tz = q[7], s_xx = q[8], s_xy = q[9],
        s_xz = q[10], s_yy = q[11], s_yz = q[12], s_zz = q[13];
  float T0 = q[14], T1 = q[15], T2 = q[16], T3 = q[17], T4 = q[18],
        T5 = q[19], T6 = q[20], T7 = q[21], T8 = q[22];
  q[0] = 0.5f * sv;
  q[1] = p1 * g0; q[2] = p1 * g1; q[3] = p1 * g2; q[4] = p1 * g3;
  q[5]  = p2s * g0 * g1 + p1 * s_tx;
  q[6]  = p2s * g0 * g2 + p1 * s_ty;
  q[7]  = p2s * g0 * g3 + p1 * s_tz;
  q[8]  = p2s * g1 * g1 + p1 * s_xx;
  q[9]  = p2s * g1 * g2 + p1 * s_xy;
  q[10] = p2s * g1 * g3 + p1 * s_xz;
  q[11] = p2s * g2 * g2 + p1 * s_yy;
  q[12] = p2s * g2 * g3 + p1 * s_yz;
  q[13] = p2s * g3 * g3 + p1 * s_zz;
  q[14] = p3t * g1 * g1 * g1 + p2t * (3.0f * s_xx * g1)              + p1 * T0;
  q[15] = p3t * g2 * g1 * g1 + p2t * (2.0f * s_xy * g1 + s_xx * g2)  + p1 * T1;
  q[16] = p3t * g3 * g1 * g1 + p2t * (2.0f * s_xz * g1 + s_xx * g3)  + p1 * T2;
  q[17] = p3t * g1 * g2 * g2 + p2t * (2.0f * s_xy * g2 + s_yy * g1)  + p1 * T3;
  q[18] = p3t * g2 * g2 * g2 + p2t * (3.0f * s_yy * g2)              + p1 * T4;
  q[19] = p3t * g3 * g2 * g2 + p2t * (2.0f * s_yz * g2 + s_yy * g3)  + p1 * T5;
  q[20] = p3t * g1 * g3 * g3 + p2t * (2.0f * s_xz * g3 + s_zz * g1)  + p1 * T6;
  q[21] = p3t * g2 * g3 * g3 + p2t * (2.0f * s_yz * g3 + s_zz * g2)  + p1 * T7;
  q[22] = p3t * g3 * g3 * g3 + p2t * (3.0f * s_zz * g3)              + p1 * T8;
  float br = q[23] - floorf(q[23]);
  q[23] = 0.5f * __builtin_amdgcn_sinf(br);
}

// k-slot permutation: neuron j sits at slot s = 32*(j>>5) + 2*(j&15) + ((j>>4)&1)
// With s = ks*32 + quad*8 + e:  j = 32*ks + 16*(e&1) + 4*quad + (e>>1)
// ---------------- prep: weights as B-operand (single fp16) + RNG + out=0 --
// wsh: [l][nt(8)][ks(4)][nl(16)][quad(4)][e(8)]  (fp16 bits)
// aoh: [ks(4)][nl(16)][quad(4)][e(8)]
__global__ __launch_bounds__(256) void prep_kernel(
    const float* __restrict__ W_hid, const float* __restrict__ W_out,
    unsigned short* __restrict__ wsh, unsigned short* __restrict__ aoh,
    float4* __restrict__ rnd, float* __restrict__ out) {
  int b = blockIdx.x;
  if (b == 0 && threadIdx.x == 0) out[0] = 0.0f;
  if (b < 320) {
    int idx = b * 256 + threadIdx.x;          // [l][nt][ks][nl][quad][e]
    int l = idx >> 14, r = idx & 16383;
    int nt = r >> 11, r2 = r & 2047;
    int ks = r2 >> 9, r3 = r2 & 511;
    int nl = r3 >> 5, r4 = r3 & 31;
    int quad = r4 >> 3, e = r4 & 7;
    int jin  = 32 * ks + 16 * (e & 1) + 4 * quad + (e >> 1);
    int jout = nt * 16 + nl;
    wsh[idx] = f2h_bits(W_hid[(l << 14) + (jin << 7) + jout]);
  } else if (b < 328) {
    int idx = (b - 320) * 256 + threadIdx.x;  // 0..2047: [ks][nl][quad][e]
    int ks = idx >> 9, r3 = idx & 511;
    int nl = r3 >> 5, r4 = r3 & 31;
    int quad = r4 >> 3, e = r4 & 7;
    int jin = 32 * ks + 16 * (e & 1) + 4 * quad + (e >> 1);
    aoh[idx] = f2h_bits((nl < 4) ? W_out[jin * 4 + nl] : 0.0f);
  } else {
    int pt = (b - 328) * 256 + threadIdx.x;
    float xb1, xb2; unsigned zbit;
    bnd_rand(pt, xb1, xb2, zbit);
    rnd[pt] = make_float4(xb1, xb2, (float)zbit, zbit ? -0.5f : 0.5f);
  }
}

// ---------------- main kernel ----------------
// LDS 53760 B: two jet planes (A-operand layout, 96 rows x 136 fp16) + Osm.
// Flipped GEMM: A=jets(M=96), B=W fp16 (N=128). One barrier per layer;
// in-register activation; next-layer weights prefetched into VGPRs.
__global__ __launch_bounds__(BS, 3) void pinn_kernel(
    const float* __restrict__ inputs, const float* __restrict__ y_true,
    const float* __restrict__ W_in,  const float* __restrict__ b_in,
    const float* __restrict__ b_hid, const float* __restrict__ b_out,
    const unsigned short* __restrict__ wsh,
    const unsigned short* __restrict__ aoh,
    const float4* __restrict__ rnd,
    float* __restrict__ out)
{
  __shared__ __align__(16) unsigned char smem[53760];
  _Float16* plane0 = (_Float16*)smem;
  _Float16* plane1 = (_Float16*)(smem + PLSZ);
  float* Osm = (float*)(smem + OSM_OFF);

  const int t    = threadIdx.x;
  const int wave = t >> 6;
  const int lane = t & 63;
  const int q    = lane >> 4;          // quad = point p in C-layout
  const int nl   = lane & 15;
  const int P    = 16 * wave + nl;     // k-slot pair id for jet writes
  const int ja   = 32 * wave + nl;     // neuron of n-tile 2*wave
  const int jb   = ja + 16;            // neuron of n-tile 2*wave+1
  const int pt0  = blockIdx.x * PPB;

  const half8* wh8 = (const half8*)wsh;
  const half8* oh8 = (const half8*)aoh;

  // prefetch layer-0 weights (no dependence on anything)
  half8 wr[2][8];
#pragma unroll
  for (int z = 0; z < 8; ++z) {
    int i = z >> 2, ks = z & 3;
    wr[0][z] = wh8[((2 * wave + i) * 4 + ks) * 64 + nl * 4 + q];
  }

  // ---- layer 1 (4 -> 128): thread (p1 = wave, P1 = lane) -> neurons j1a,j1b
  {
    const int p1 = t >> 6;
    const int P1 = lane;
    const int j1a = 32 * (P1 >> 4) + (P1 & 15), j1b = j1a + 16;
    const int pt = pt0 + p1;
    float4 rv = rnd[pt];
    float x_t = inputs[pt * 4 + 0], x_x = inputs[pt * 4 + 1];
    float x_y = inputs[pt * 4 + 2], x_z = inputs[pt * 4 + 3];
    float q0[NCH], q1[NCH];
#pragma unroll
    for (int h = 0; h < 2; ++h) {
      int jj = h ? j1b : j1a;
      float* qq = h ? q1 : q0;
      float w0 = W_in[0 * DD + jj], w1 = W_in[1 * DD + jj],
            w2 = W_in[2 * DD + jj], w3 = W_in[3 * DD + jj];
      float bb = b_in[jj];
      qq[0] = bb + x_t * w0 + x_x * w1 + x_y * w2 + x_z * w3;
      qq[1] = w0; qq[2] = w1; qq[3] = w2; qq[4] = w3;
#pragma unroll
      for (int c = 5; c < 23; ++c) qq[c] = 0.0f;
      qq[23] = bb + x_t * w0 + rv.x * w1 + rv.y * w2 + rv.z * w3;
      activate_jet(qq);
    }
    unsigned* dw = (unsigned*)plane0;
#pragma unroll
    for (int c = 0; c < NCH; ++c)
      dw[ROWM(p1, c) * WPW + P1] = pk2(q0[c], q1[c]);
  }
  __syncthreads();

  // ---- hidden layers: flipped GEMM M=96(jets) x N=128(neurons) x K=128
#pragma unroll
  for (int l = 0; l < NHID; ++l) {
    const half8* src = (const half8*)((l & 1) ? plane1 : plane0);
    unsigned* dstw = (unsigned*)((l & 1) ? plane0 : plane1);

    f32x4 acc[6][2];
#pragma unroll
    for (int mt = 0; mt < 6; ++mt) { acc[mt][0] = (f32x4)0.0f; acc[mt][1] = (f32x4)0.0f; }

#pragma unroll
    for (int ks = 0; ks < 4; ++ks) {
      half8 a[6];
#pragma unroll
      for (int mt = 0; mt < 6; ++mt)
        a[mt] = src[(16 * mt + nl) * WP8 + ks * 4 + q];
#pragma unroll
      for (int mt = 0; mt < 6; ++mt)
#pragma unroll
        for (int i = 0; i < 2; ++i)
          acc[mt][i] = __builtin_amdgcn_mfma_f32_16x16x32_f16(a[mt], wr[l & 1][i * 4 + ks], acc[mt][i], 0, 0, 0);
    }

    // prefetch next layer's weights (overlaps with activation VALU)
    if (l + 1 < NHID) {
#pragma unroll
      for (int z = 0; z < 8; ++z) {
        int i = z >> 2, ks = z & 3;
        wr[(l + 1) & 1][z] = wh8[(((l + 1) * 8 + 2 * wave + i) * 4 + ks) * 64 + nl * 4 + q];
      }
    }

    // in-register activation: lane holds all 24 channels of point q for ja, jb
    float qa[NCH], qb[NCH];
#pragma unroll
    for (int mt = 0; mt < 6; ++mt)
#pragma unroll
      for (int r = 0; r < 4; ++r) {
        qa[4 * mt + r] = acc[mt][0][r];
        qb[4 * mt + r] = acc[mt][1][r];
      }
    float ba = b_hid[l * DD + ja], bb_ = b_hid[l * DD + jb];
    qa[0] += ba; qa[23] += ba;
    qb[0] += bb_; qb[23] += bb_;
    activate_jet(qa);
    activate_jet(qb);
#pragma unroll
    for (int c = 0; c < NCH; ++c)
      dstw[ROWM(q, c) * WPW + P] = pk2(qa[c], qb[c]);
    __syncthreads();   // dst plane complete; src plane reads all done
  }

  // ---- output layer: A = final jets (plane1), B = W_out padded (N=16)
  {
    const half8* src = (const half8*)plane1;   // NHID odd -> final in plane1
    if (wave < 3) {
      f32x4 acc2[2];
      acc2[0] = (f32x4)0.0f; acc2[1] = (f32x4)0.0f;
#pragma unroll
      for (int ks = 0; ks < 4; ++ks) {
        half8 a0 = src[(16 * (2 * wave)     + nl) * WP8 + ks * 4 + q];
        half8 a1 = src[(16 * (2 * wave + 1) + nl) * WP8 + ks * 4 + q];
        half8 oh = oh8[ks * 64 + nl * 4 + q];
        acc2[0] = __builtin_amdgcn_mfma_f32_16x16x32_f16(a0, oh, acc2[0], 0, 0, 0);
        acc2[1] = __builtin_amdgcn_mfma_f32_16x16x32_f16(a1, oh, acc2[1], 0, 0, 0);
      }
      if (nl < 4) {
#pragma unroll
        for (int i = 0; i < 2; ++i)
#pragma unroll
          for (int r = 0; r < 4; ++r)
            Osm[(q * NCH + 4 * (2 * wave + i) + r) * 4 + nl] = acc2[i][r];
      }
    }
  }
  __syncthreads();     // Osm ready

  // ---- loss epilogue: threads 0..3 (one point each)
  if (t < PPB) {
    const int pp = t;
    const int ptt = pt0 + pp;
    const float Ttrue = rnd[ptt].w;
    const float SEC  = SS_INV;                              // 2nd-deriv unscale
    const float SCT  = 8.36660026534e-04f * ST_INV;         // sqrt(Pr/Ra)*2^16
    const float KAPS = 1.19522860933e-03f * SS_INV;         // kappa*2^10
    float bo0 = b_out[0], bo1 = b_out[1], bo2 = b_out[2], bo3 = b_out[3];
#define OO(o, c) Osm[(pp * NCH + (c)) * 4 + (o)]
    float u  = OO(0, 0) + bo0, v_ = OO(1, 0) + bo1, w_ = OO(2, 0) + bo2;
    float ux = OO(0, 2), uy = OO(0, 3), uz = OO(0, 4);
    float vx = OO(1, 2), vy = OO(1, 3), vz = OO(1, 4);
    float wx = OO(2, 2), wy = OO(2, 3), wz = OO(2, 4);
    float Tt = OO(3, 1), Tx = OO(3, 2), Ty = OO(3, 3), Tz = OO(3, 4);

    float hu = OO(2, 6) - OO(1, 7)
             + u  * (OO(2, 9)  - OO(1, 10))
             + v_ * (OO(2, 11) - OO(1, 12))
             + w_ * (OO(2, 12) - OO(1, 13));
    float NSEu = SEC * hu
               - (wy - vz) * ux - (uz - wx) * uy - (vx - uy) * uz
               - SCT * (OO(2, 15) - OO(1, 16) + OO(2, 18) - OO(1, 19) + OO(2, 21) - OO(1, 22))
               - Ty;
    float hv = OO(0, 7) - OO(2, 5)
             + u  * (OO(0, 10) - OO(2, 8))
             + v_ * (OO(0, 12) - OO(2, 9))
             + w_ * (OO(0, 13) - OO(2, 10));
    float NSEv = SEC * hv
               - (wy - vz) * vx - (uz - wx) * vy - (vx - uy) * vz
               - SCT * (OO(0, 16) - OO(2, 14) + OO(0, 19) - OO(2, 17) + OO(0, 22) - OO(2, 20))
               + Tx;
    float hw = OO(1, 5) - OO(0, 6)
             + u  * (OO(1, 8)  - OO(0, 9))
             + v_ * (OO(1, 9)  - OO(0, 11))
             + w_ * (OO(1, 10) - OO(0, 12));
    float NSEw = SEC * hw
               - (wy - vz) * wx - (uz - wx) * wy - (vx - uy) * wz
               - SCT * (OO(1, 14) - OO(0, 15) + OO(1, 17) - OO(0, 18) + OO(1, 20) - OO(0, 21));

    float EE = Tt + u * Tx + v_ * Ty + w_ * Tz
             - KAPS * (OO(3, 8) + OO(3, 11) + OO(3, 13));

    float conti = ux + vy + wz;
    const float* yt = y_true + ptt * 4;
    float d0 = u - yt[0], d1 = v_ - yt[1], d2 = w_ - yt[2];
    float dT = Ttrue - (OO(3, 23) + bo3);
#undef OO
    const float invN  = 1.0f / (float)NPTS;
    const float inv3N = 1.0f / (3.0f * (float)NPTS);
    float part = (d0 * d0 + d1 * d1 + d2 * d2) * inv3N
               + conti * conti * invN
               + (NSEu * NSEu + NSEv * NSEv + NSEw * NSEw) * inv3N
               + EE * EE * invN
               + dT * dT * invN;
    atomicAdd(out, part);
  }
}

extern "C" void kernel_launch(void* const* d_in, const int* in_sizes, int n_in,
                              void* d_out, int out_size, void* d_ws, size_t ws_size,
                              hipStream_t stream) {
  const float* inputs = (const float*)d_in[0];
  const float* y_true = (const float*)d_in[1];
  const float* W_in   = (const float*)d_in[2];
  const float* b_in   = (const float*)d_in[3];
  const float* W_hid  = (const float*)d_in[4];
  const float* b_hid  = (const float*)d_in[5];
  const float* W_out  = (const float*)d_in[6];
  const float* b_out  = (const float*)d_in[7];
  float* out = (float*)d_out;

  unsigned char* ws = (unsigned char*)d_ws;
  unsigned short* wsh = (unsigned short*)(ws);             // 163840 B
  unsigned short* aoh = (unsigned short*)(ws + 163840);    // 4096 B
  float4*         rnd = (float4*)(ws + 167936);            // 65536 B

  prep_kernel<<<344, 256, 0, stream>>>(W_hid, W_out, wsh, aoh, rnd, out);
  pinn_kernel<<<NPTS / PPB, BS, 0, stream>>>(inputs, y_true, W_in, b_in,
                                             b_hid, b_out, wsh, aoh, rnd, out);
}